// Round 5
// baseline (688.011 us; speedup 1.0000x reference)
//
#include <hip/hip_runtime.h>

typedef unsigned short bf16_t;
typedef short short8 __attribute__((ext_vector_type(8)));
typedef float f32x4 __attribute__((ext_vector_type(4)));

static __device__ __forceinline__ unsigned short f2bf(float f) {
  unsigned int u = __float_as_uint(f);
  unsigned int r = (u + 0x7FFFu + ((u >> 16) & 1u)) >> 16;
  return (unsigned short)r;
}
static __device__ __forceinline__ unsigned short f2bf_fast(float f) {
  return (unsigned short)((__float_as_uint(f) + 0x8000u) >> 16);
}
static __device__ __forceinline__ float bf2f(unsigned short u) {
  return __uint_as_float((unsigned int)u << 16);
}

__device__ __forceinline__ void gload_lds16(const void* g, void* l) {
  __builtin_amdgcn_global_load_lds((const __attribute__((address_space(1))) void*)g,
                                   (__attribute__((address_space(3))) void*)l,
                                   16, 0, 0);
}

// ---------------------------------------------------------------------------
// Fused prep: blocks [0,4096) transpose Wq/Wk/Wv/Wo (1024x1024 each);
// [4096,8192) W1 (1024x4096); [8192,12288) W2 (4096x1024);
// [12288,16384) LayerNorm rows of x.
// ---------------------------------------------------------------------------
__global__ __launch_bounds__(256) void prep_kernel(
    const float* __restrict__ Wq, const float* __restrict__ Wk,
    const float* __restrict__ Wv, const float* __restrict__ Wo,
    const float* __restrict__ W1, const float* __restrict__ W2,
    const float* __restrict__ x, const float* __restrict__ g1,
    const float* __restrict__ be1,
    bf16_t* __restrict__ WqkvT, bf16_t* __restrict__ W1T,
    bf16_t* __restrict__ W2T, bf16_t* __restrict__ xnb) {
  __shared__ float tile[32][33];
  const int bid = blockIdx.x;
  if (bid < 12288) {
    const float* src;
    bf16_t* dst;
    int rows, cols, bx, by;
    if (bid < 4096) {
      const int z = bid >> 10, r = bid & 1023;
      src = (z == 0) ? Wq : (z == 1) ? Wk : (z == 2) ? Wv : Wo;
      dst = WqkvT + (size_t)z * 1048576;
      rows = 1024; cols = 1024;
      bx = (r & 31) * 32; by = (r >> 5) * 32;
    } else if (bid < 8192) {
      const int r = bid - 4096;
      src = W1; dst = W1T; rows = 1024; cols = 4096;
      bx = (r & 127) * 32; by = (r >> 7) * 32;
    } else {
      const int r = bid - 8192;
      src = W2; dst = W2T; rows = 4096; cols = 1024;
      bx = (r & 31) * 32; by = (r >> 5) * 32;
    }
    const int tx = threadIdx.x & 31, ty = threadIdx.x >> 5;
#pragma unroll
    for (int i = 0; i < 32; i += 8)
      tile[ty + i][tx] = src[(size_t)(by + ty + i) * cols + (bx + tx)];
    __syncthreads();
#pragma unroll
    for (int i = 0; i < 32; i += 8)
      dst[(size_t)(bx + ty + i) * rows + (by + tx)] = f2bf(tile[tx][ty + i]);
  } else {
    const int row = bid - 12288;
    const int tid = threadIdx.x;
    const float4 v = reinterpret_cast<const float4*>(x + (size_t)row * 1024)[tid];
    float s = v.x + v.y + v.z + v.w;
    float ss = v.x * v.x + v.y * v.y + v.z * v.z + v.w * v.w;
#pragma unroll
    for (int off = 32; off; off >>= 1) {
      s += __shfl_xor(s, off, 64);
      ss += __shfl_xor(ss, off, 64);
    }
    float* red = &tile[0][0];
    const int wave = tid >> 6, lane = tid & 63;
    if (lane == 0) { red[wave] = s; red[4 + wave] = ss; }
    __syncthreads();
    const float mu = (red[0] + red[1] + red[2] + red[3]) * (1.f / 1024.f);
    const float ms = (red[4] + red[5] + red[6] + red[7]) * (1.f / 1024.f);
    const float rstd = rsqrtf(ms - mu * mu + 1e-5f);
    const float4 gg = reinterpret_cast<const float4*>(g1)[tid];
    const float4 bb = reinterpret_cast<const float4*>(be1)[tid];
    bf16_t* o = xnb + (size_t)row * 1024 + tid * 4;
    o[0] = f2bf((v.x - mu) * rstd * gg.x + bb.x);
    o[1] = f2bf((v.y - mu) * rstd * gg.y + bb.y);
    o[2] = f2bf((v.z - mu) * rstd * gg.z + bb.z);
    o[3] = f2bf((v.w - mu) * rstd * gg.w + bb.w);
  }
}

// ---------------------------------------------------------------------------
// LN2-combine: x2 = sum(4 bf16 partials)+bo+x ; x2 f32 out + xn2 = LN(x2) bf16
// ---------------------------------------------------------------------------
__global__ __launch_bounds__(256) void ln2_combine(const bf16_t* __restrict__ p,
                                                   const float* __restrict__ x,
                                                   const float* __restrict__ bo,
                                                   const float* __restrict__ g,
                                                   const float* __restrict__ be,
                                                   float* __restrict__ x2,
                                                   bf16_t* __restrict__ xn) {
  const int row = blockIdx.x;
  const int tid = threadIdx.x;
  const float4 xv = reinterpret_cast<const float4*>(x + (size_t)row * 1024)[tid];
  const float4 bb = reinterpret_cast<const float4*>(bo)[tid];
  float4 v = {bb.x + xv.x, bb.y + xv.y, bb.z + xv.z, bb.w + xv.w};
#pragma unroll
  for (int z = 0; z < 4; ++z) {
    const ushort4 a = reinterpret_cast<const ushort4*>(p + (size_t)z * 4194304 + (size_t)row * 1024)[tid];
    v.x += bf2f(a.x); v.y += bf2f(a.y); v.z += bf2f(a.z); v.w += bf2f(a.w);
  }
  reinterpret_cast<float4*>(x2 + (size_t)row * 1024)[tid] = v;
  float s = v.x + v.y + v.z + v.w;
  float ss = v.x * v.x + v.y * v.y + v.z * v.z + v.w * v.w;
#pragma unroll
  for (int off = 32; off; off >>= 1) {
    s += __shfl_xor(s, off, 64);
    ss += __shfl_xor(ss, off, 64);
  }
  __shared__ float red[8];
  const int wave = tid >> 6, lane = tid & 63;
  if (lane == 0) { red[wave] = s; red[4 + wave] = ss; }
  __syncthreads();
  const float mu = (red[0] + red[1] + red[2] + red[3]) * (1.f / 1024.f);
  const float ms = (red[4] + red[5] + red[6] + red[7]) * (1.f / 1024.f);
  const float rstd = rsqrtf(ms - mu * mu + 1e-5f);
  const float4 gg = reinterpret_cast<const float4*>(g)[tid];
  const float4 eb = reinterpret_cast<const float4*>(be)[tid];
  bf16_t* o = xn + (size_t)row * 1024 + tid * 4;
  o[0] = f2bf((v.x - mu) * rstd * gg.x + eb.x);
  o[1] = f2bf((v.y - mu) * rstd * gg.y + eb.y);
  o[2] = f2bf((v.z - mu) * rstd * gg.z + eb.z);
  o[3] = f2bf((v.w - mu) * rstd * gg.w + eb.w);
}

// ---------------------------------------------------------------------------
// FFN combine: out = bf(p0)+bf(p1)+bf(p2)+b2+x2
// ---------------------------------------------------------------------------
__global__ __launch_bounds__(256) void ffn_combine(const bf16_t* __restrict__ p0,
                                                   const bf16_t* __restrict__ p2,
                                                   const float* __restrict__ x2,
                                                   const float* __restrict__ b2,
                                                   float* __restrict__ out) {
  const int row = blockIdx.x;
  const int tid = threadIdx.x;
  const ushort4 a0 = reinterpret_cast<const ushort4*>(p0 + (size_t)row * 1024)[tid];
  const ushort4 a1 = reinterpret_cast<const ushort4*>(p0 + 4194304 + (size_t)row * 1024)[tid];
  const ushort4 a2 = reinterpret_cast<const ushort4*>(p2 + (size_t)row * 1024)[tid];
  const float4 xv = reinterpret_cast<const float4*>(x2 + (size_t)row * 1024)[tid];
  const float4 bb = reinterpret_cast<const float4*>(b2)[tid];
  float4 v;
  v.x = bf2f(a0.x) + bf2f(a1.x) + bf2f(a2.x) + bb.x + xv.x;
  v.y = bf2f(a0.y) + bf2f(a1.y) + bf2f(a2.y) + bb.y + xv.y;
  v.z = bf2f(a0.z) + bf2f(a1.z) + bf2f(a2.z) + bb.z + xv.z;
  v.w = bf2f(a0.w) + bf2f(a1.w) + bf2f(a2.w) + bb.w + xv.w;
  reinterpret_cast<float4*>(out + (size_t)row * 1024)[tid] = v;
}

// ---------------------------------------------------------------------------
// RoPE in place on bf16 q,k [B,H,S,64]; q scaled by (1/8)*log2(e) so the
// attention softmax can use exp2 directly.
// ---------------------------------------------------------------------------
__global__ __launch_bounds__(256) void rope_bf16(bf16_t* __restrict__ q,
                                                 bf16_t* __restrict__ k) {
  const int id = blockIdx.x * 256 + threadIdx.x;
  const int i = id & 31;
  const int s = (id >> 5) & 2047;
  const int bh = id >> 16;
  const float inv = exp2f((float)i * -0.41524101186f);
  float sn, cs;
  sincosf((float)s * inv, &sn, &cs);
  const size_t base = ((size_t)bh * 2048 + s) * 64 + 2 * i;
  unsigned int qp = *(unsigned int*)&q[base];
  unsigned int kp = *(unsigned int*)&k[base];
  const float q0 = bf2f(qp & 0xffff), q1 = bf2f(qp >> 16);
  const float k0 = bf2f(kp & 0xffff), k1 = bf2f(kp >> 16);
  const float qs = 0.18033688f;  // 0.125 * log2(e)
  const unsigned int qo =
      (unsigned int)f2bf((q0 * cs - q1 * sn) * qs) |
      ((unsigned int)f2bf((q0 * sn + q1 * cs) * qs) << 16);
  const unsigned int ko =
      (unsigned int)f2bf(k0 * cs - k1 * sn) |
      ((unsigned int)f2bf(k0 * sn + k1 * cs) << 16);
  *(unsigned int*)&q[base] = qo;
  *(unsigned int*)&k[base] = ko;
}

// ---------------------------------------------------------------------------
// MFMA flash attention, 8 waves/block for TLP (32 waves/CU at VGPR<=64).
// grid (32 bh, 32), block 512: qsub=wave&1 (32 q rows), kh=wave>>1 (512-K
// quarter). No barriers in main loop (per-wave LDS P tile). End: 2-stage
// LDS tree merge of the 4 K-partials.
// ---------------------------------------------------------------------------
__global__ __launch_bounds__(512, 8) void attn4(const bf16_t* __restrict__ qb,
                                                const bf16_t* __restrict__ kb,
                                                const bf16_t* __restrict__ vt,
                                                bf16_t* __restrict__ out) {
  const int bh = blockIdx.x;
  const int tid = threadIdx.x, wave = tid >> 6, lane = tid & 63;
  const int col = lane & 15, quad = lane >> 4;
  const int qsub = wave & 1, kh = wave >> 1;
  const int q0 = blockIdx.y * 64 + qsub * 32;
  const size_t kvb = (size_t)bh * (2048 * 64);

  // union: psw 8*32*72*2 = 36864 B ; combine accA 4*64*32*4 = 32768 B +
  // lsA 4*32*4 = 512 B (33280 B). 4 blocks/CU -> 147456 B of 160 KiB.
  __shared__ __align__(16) char smem[36864];
  bf16_t* psw = (bf16_t*)smem + wave * (32 * 72);

  short8 qf[2][2];
#pragma unroll
  for (int mi = 0; mi < 2; ++mi)
#pragma unroll
    for (int ks = 0; ks < 2; ++ks)
      qf[mi][ks] = *(const short8*)&qb[kvb + (size_t)(q0 + mi * 16 + col) * 64 + ks * 32 + quad * 8];

  f32x4 acc[2][4];
  float lsum[2][4];
#pragma unroll
  for (int mi = 0; mi < 2; ++mi)
#pragma unroll
    for (int n = 0; n < 4; ++n) acc[mi][n] = (f32x4){0.f, 0.f, 0.f, 0.f};
#pragma unroll
  for (int mi = 0; mi < 2; ++mi)
#pragma unroll
    for (int r = 0; r < 4; ++r) lsum[mi][r] = 0.f;

  for (int it = 0; it < 8; ++it) {
    const int t = kh * 512 + it * 64;
    f32x4 sc[2][4];
#pragma unroll
    for (int mi = 0; mi < 2; ++mi)
#pragma unroll
      for (int n = 0; n < 4; ++n) sc[mi][n] = (f32x4){0.f, 0.f, 0.f, 0.f};
#pragma unroll
    for (int ks = 0; ks < 2; ++ks) {
      short8 kf[4];
#pragma unroll
      for (int n = 0; n < 4; ++n)
        kf[n] = *(const short8*)&kb[kvb + (size_t)(t + n * 16 + col) * 64 + ks * 32 + quad * 8];
#pragma unroll
      for (int mi = 0; mi < 2; ++mi)
#pragma unroll
        for (int n = 0; n < 4; ++n)
          sc[mi][n] = __builtin_amdgcn_mfma_f32_16x16x32_bf16(qf[mi][ks], kf[n], sc[mi][n], 0, 0, 0);
    }
    // exp2 (no max), per-lane partial row-sum, P -> LDS (C->A layout)
#pragma unroll
    for (int mi = 0; mi < 2; ++mi)
#pragma unroll
      for (int n = 0; n < 4; ++n)
#pragma unroll
        for (int r = 0; r < 4; ++r) {
          const float pv = exp2f(sc[mi][n][r]);
          lsum[mi][r] += pv;
          psw[(mi * 16 + quad * 4 + r) * 72 + n * 16 + col] = f2bf_fast(pv);
        }
    short8 pf[2][2];
#pragma unroll
    for (int mi = 0; mi < 2; ++mi)
#pragma unroll
      for (int ks = 0; ks < 2; ++ks)
        pf[mi][ks] = *(const short8*)&psw[(mi * 16 + col) * 72 + ks * 32 + quad * 8];
#pragma unroll
    for (int ks = 0; ks < 2; ++ks) {
      short8 vf[4];
#pragma unroll
      for (int n = 0; n < 4; ++n)
        vf[n] = *(const short8*)&vt[kvb + (size_t)(n * 16 + col) * 2048 + t + ks * 32 + quad * 8];
#pragma unroll
      for (int mi = 0; mi < 2; ++mi)
#pragma unroll
        for (int n = 0; n < 4; ++n)
          acc[mi][n] = __builtin_amdgcn_mfma_f32_16x16x32_bf16(pf[mi][ks], vf[n], acc[mi][n], 0, 0, 0);
    }
  }

  // reduce lsum across the 16 col-lanes (row total per (kh,qsub) partial)
#pragma unroll
  for (int mi = 0; mi < 2; ++mi)
#pragma unroll
    for (int r = 0; r < 4; ++r) {
      float s = lsum[mi][r];
      s += __shfl_xor(s, 1, 64);
      s += __shfl_xor(s, 2, 64);
      s += __shfl_xor(s, 4, 64);
      s += __shfl_xor(s, 8, 64);
      lsum[mi][r] = s;
    }

  float* accA = (float*)smem;            // [4 slots][64 lanes][32]
  float* lsA = (float*)(smem + 32768);   // [4 slots][32 rows]

  // stage 1: kh=2,3 publish
  __syncthreads();
  if (kh >= 2) {
    const int slot = (kh - 2) * 2 + qsub;
    float* w = accA + (size_t)(slot * 64 + lane) * 32;
#pragma unroll
    for (int mi = 0; mi < 2; ++mi)
#pragma unroll
      for (int n = 0; n < 4; ++n)
#pragma unroll
        for (int r = 0; r < 4; ++r) w[mi * 16 + n * 4 + r] = acc[mi][n][r];
    if (col == 0) {
#pragma unroll
      for (int mi = 0; mi < 2; ++mi)
#pragma unroll
        for (int r = 0; r < 4; ++r) lsA[slot * 32 + mi * 16 + quad * 4 + r] = lsum[mi][r];
    }
  }
  __syncthreads();
  // stage 2: kh=0 merges kh=2 (slot qsub); kh=1 merges kh=3 (slot 2+qsub)
  if (kh < 2) {
    const int slot = kh * 2 + qsub;
    const float* w = accA + (size_t)(slot * 64 + lane) * 32;
#pragma unroll
    for (int mi = 0; mi < 2; ++mi)
#pragma unroll
      for (int n = 0; n < 4; ++n)
#pragma unroll
        for (int r = 0; r < 4; ++r) acc[mi][n][r] += w[mi * 16 + n * 4 + r];
#pragma unroll
    for (int mi = 0; mi < 2; ++mi)
#pragma unroll
      for (int r = 0; r < 4; ++r) lsum[mi][r] += lsA[slot * 32 + mi * 16 + quad * 4 + r];
  }
  __syncthreads();
  // stage 3: kh=1 publishes merged half
  if (kh == 1) {
    const int slot = qsub;
    float* w = accA + (size_t)(slot * 64 + lane) * 32;
#pragma unroll
    for (int mi = 0; mi < 2; ++mi)
#pragma unroll
      for (int n = 0; n < 4; ++n)
#pragma unroll
        for (int r = 0; r < 4; ++r) w[mi * 16 + n * 4 + r] = acc[mi][n][r];
    if (col == 0) {
#pragma unroll
      for (int mi = 0; mi < 2; ++mi)
#pragma unroll
        for (int r = 0; r < 4; ++r) lsA[slot * 32 + mi * 16 + quad * 4 + r] = lsum[mi][r];
    }
  }
  __syncthreads();
  // stage 4: kh=0 final merge + store
  if (kh == 0) {
    const int slot = qsub;
    const float* w = accA + (size_t)(slot * 64 + lane) * 32;
#pragma unroll
    for (int mi = 0; mi < 2; ++mi)
#pragma unroll
      for (int n = 0; n < 4; ++n)
#pragma unroll
        for (int r = 0; r < 4; ++r) acc[mi][n][r] += w[mi * 16 + n * 4 + r];
    const int b = bh >> 4, h = bh & 15;
#pragma unroll
    for (int mi = 0; mi < 2; ++mi)
#pragma unroll
      for (int r = 0; r < 4; ++r) {
        const float rl = 1.f / (lsum[mi][r] + lsA[slot * 32 + mi * 16 + quad * 4 + r]);
        const size_t ro = (size_t)(b * 2048 + q0 + mi * 16 + quad * 4 + r) * 1024 + h * 64;
#pragma unroll
        for (int n = 0; n < 4; ++n) out[ro + n * 16 + col] = f2bf(acc[mi][n][r] * rl);
      }
  }
}

// ---------------------------------------------------------------------------
// bf16 MFMA GEMM, C = A[M][K] @ BT[N][K]^T (m97 structure). Epilogue per MODE.
// Split-K via blockIdx.z: k-range [z*kspan, min(z*kspan+kspan, K)).
// MODE_PART dst: z==2 -> ob1, else ob0 + z*4194304.
// ---------------------------------------------------------------------------
enum { MODE_QKV = 0, MODE_FF1 = 1, MODE_PART = 2 };

template <int MODE>
__global__ __launch_bounds__(256) void gemm_bt(
    const bf16_t* __restrict__ A, const bf16_t* __restrict__ BT,
    int M, int N, int K, int kspan,
    const float* __restrict__ bias0, const float* __restrict__ bias1,
    const float* __restrict__ bias2,
    bf16_t* __restrict__ ob0, bf16_t* __restrict__ ob1, bf16_t* __restrict__ ob2) {
  __shared__ __align__(16) bf16_t As[128 * 32];
  __shared__ __align__(16) bf16_t Bs[128 * 32];
  const int tid = threadIdx.x;
  const int wave = tid >> 6, lane = tid & 63;
  const int row16 = lane & 15, quad = lane >> 4;
  const int m0 = blockIdx.x * 128, n0 = blockIdx.y * 128;
  const int wm = (wave & 1) << 6, wn = (wave >> 1) << 6;

  f32x4 acc[4][4];
#pragma unroll
  for (int i = 0; i < 4; ++i)
#pragma unroll
    for (int j = 0; j < 4; ++j) acc[i][j] = (f32x4){0.f, 0.f, 0.f, 0.f};

  const int r0 = tid >> 2;
  const int kc = (tid & 3) << 3;
  const int kb = blockIdx.z * kspan;
  const int kend = (kb + kspan < K) ? kb + kspan : K;

  for (int k0 = kb; k0 < kend; k0 += 32) {
    gload_lds16(A + (size_t)(m0 + r0) * K + k0 + kc, &As[(size_t)tid * 8]);
    gload_lds16(A + (size_t)(m0 + 64 + r0) * K + k0 + kc, &As[((size_t)tid + 256) * 8]);
    gload_lds16(BT + (size_t)(n0 + r0) * K + k0 + kc, &Bs[(size_t)tid * 8]);
    gload_lds16(BT + (size_t)(n0 + 64 + r0) * K + k0 + kc, &Bs[((size_t)tid + 256) * 8]);
    __syncthreads();
    short8 af[4], bfr[4];
#pragma unroll
    for (int mi = 0; mi < 4; ++mi)
      af[mi] = *(const short8*)&As[(wm + mi * 16 + row16) * 32 + quad * 8];
#pragma unroll
    for (int ni = 0; ni < 4; ++ni)
      bfr[ni] = *(const short8*)&Bs[(wn + ni * 16 + row16) * 32 + quad * 8];
#pragma unroll
    for (int mi = 0; mi < 4; ++mi)
#pragma unroll
      for (int ni = 0; ni < 4; ++ni)
        acc[mi][ni] =
            __builtin_amdgcn_mfma_f32_16x16x32_bf16(af[mi], bfr[ni], acc[mi][ni], 0, 0, 0);
    __syncthreads();
  }

#pragma unroll
  for (int mi = 0; mi < 4; ++mi) {
    const int gm_base = m0 + wm + mi * 16 + quad * 4;
#pragma unroll
    for (int ni = 0; ni < 4; ++ni) {
      const int gn = n0 + wn + ni * 16 + row16;
#pragma unroll
      for (int r = 0; r < 4; ++r) {
        const int gm = gm_base + r;
        const float c = acc[mi][ni][r];
        if (MODE == MODE_QKV) {
          const int b = gm >> 11, s = gm & 2047;
          if (gn < 1024) {
            const int h = gn >> 6, d = gn & 63;
            ob0[(((size_t)b * 16 + h) * 2048 + s) * 64 + d] = f2bf(c + bias0[gn]);
          } else if (gn < 2048) {
            const int nn = gn - 1024, h = nn >> 6, d = nn & 63;
            ob1[(((size_t)b * 16 + h) * 2048 + s) * 64 + d] = f2bf(c + bias1[nn]);
          } else {
            const int nn = gn - 2048, h = nn >> 6, d = nn & 63;
            ob2[(((size_t)b * 16 + h) * 64 + d) * 2048 + s] = f2bf(c + bias2[nn]);
          }
        } else if (MODE == MODE_FF1) {
          ob0[(size_t)gm * N + gn] = f2bf(fmaxf(c + bias0[gn], 0.f));
        } else {  // MODE_PART
          bf16_t* dst = (blockIdx.z == 2) ? ob1 : ob0 + (size_t)blockIdx.z * 4194304;
          dst[(size_t)gm * N + gn] = f2bf(c);
        }
      }
    }
  }
}

// ---------------------------------------------------------------------------
extern "C" void kernel_launch(void* const* d_in, const int* in_sizes, int n_in,
                              void* d_out, int out_size, void* d_ws, size_t ws_size,
                              hipStream_t stream) {
  const float* x = (const float*)d_in[0];
  const float* Wq = (const float*)d_in[1];
  const float* bq = (const float*)d_in[2];
  const float* Wk = (const float*)d_in[3];
  const float* bk = (const float*)d_in[4];
  const float* Wv = (const float*)d_in[5];
  const float* bv = (const float*)d_in[6];
  const float* Wo = (const float*)d_in[7];
  const float* bo = (const float*)d_in[8];
  const float* W1 = (const float*)d_in[9];
  const float* b1 = (const float*)d_in[10];
  const float* W2 = (const float*)d_in[11];
  const float* b2 = (const float*)d_in[12];
  const float* g1 = (const float*)d_in[13];
  const float* be1 = (const float*)d_in[14];
  const float* g2 = (const float*)d_in[15];
  const float* be2 = (const float*)d_in[16];
  float* out = (float*)d_out;

  char* ws = (char*)d_ws;
  size_t off = 0;
  auto alloc = [&](size_t bytes) {
    void* p = ws + off;
    off += (bytes + 255) & ~(size_t)255;
    return p;
  };
  bf16_t* WqkvT = (bf16_t*)alloc(3072ULL * 1024 * 2);  // [0,6MB)
  bf16_t* WoT = (bf16_t*)alloc(1024ULL * 1024 * 2);    // [6,8)
  bf16_t* W1T = (bf16_t*)alloc(4096ULL * 1024 * 2);    // [8,16)
  bf16_t* W2T = (bf16_t*)alloc(1024ULL * 4096 * 2);    // [16,24)
  bf16_t* xnb = (bf16_t*)alloc(4096ULL * 1024 * 2);    // [24,32) xn1/attn_out/xn2/FF2-partial2
  bf16_t* qb = (bf16_t*)alloc(4194304ULL * 2);         // [32,40)
  bf16_t* kb = (bf16_t*)alloc(4194304ULL * 2);         // [40,48)
  bf16_t* vt = (bf16_t*)alloc(4194304ULL * 2);         // [48,56)
  (void)alloc(8ULL << 20);                             // [56,64) tail for h1/x2p
  bf16_t* h1 = qb;       // FF1 out [4096][4096] bf16 over [32,64)
  bf16_t* x2p = qb;      // X2 bf16 partials (4 x 8MB) over [32,64), pre-FF1
  bf16_t* ffp = WqkvT;   // FF2 partials 0,1 over dead weights [0,16)
  float* x2 = (float*)alloc(16777216ULL);              // [64,80)

  // fused transposes + LN1
  prep_kernel<<<16384, 256, 0, stream>>>(Wq, Wk, Wv, Wo, W1, W2, x, g1, be1,
                                         WqkvT, W1T, W2T, xnb);

  gemm_bt<MODE_QKV><<<dim3(32, 24, 1), 256, 0, stream>>>(xnb, WqkvT, 4096, 3072, 1024, 1024,
                                                         bq, bk, bv, qb, kb, vt);

  rope_bf16<<<8192, 256, 0, stream>>>(qb, kb);

  attn4<<<dim3(32, 32), 512, 0, stream>>>(qb, kb, vt, xnb);

  // X2 = attn_out @ Wo, split-K=4 -> bf16 partials over dead q/k/v/tail
  gemm_bt<MODE_PART><<<dim3(32, 8, 4), 256, 0, stream>>>(xnb, WoT, 4096, 1024, 1024, 256,
                                                         nullptr, nullptr, nullptr,
                                                         x2p, x2p + 2 * 4194304, nullptr);

  // x2 = sum(partials)+bo+x ; xn2 = LN(x2)
  ln2_combine<<<4096, 256, 0, stream>>>(x2p, x, bo, g2, be2, x2, xnb);

  gemm_bt<MODE_FF1><<<dim3(32, 32, 1), 256, 0, stream>>>(xnb, W1T, 4096, 4096, 1024, 1024,
                                                         b1, nullptr, nullptr,
                                                         h1, nullptr, nullptr);

  // FF2 = h1 @ W2, split-K=3 (1376/1376/1344): partials 0,1 over dead weights,
  // partial 2 over dead xnb
  gemm_bt<MODE_PART><<<dim3(32, 8, 3), 256, 0, stream>>>(h1, W2T, 4096, 1024, 4096, 1376,
                                                         nullptr, nullptr, nullptr,
                                                         ffp, xnb, nullptr);

  // out = p0+p1+p2+b2+x2
  ffn_combine<<<4096, 256, 0, stream>>>(ffp, xnb, x2, b2, out);
}

// Round 6
// 476.438 us; speedup vs baseline: 1.4441x; 1.4441x over previous
//
#include <hip/hip_runtime.h>

typedef unsigned short bf16_t;
typedef short short8 __attribute__((ext_vector_type(8)));
typedef float f32x4 __attribute__((ext_vector_type(4)));

static __device__ __forceinline__ unsigned short f2bf(float f) {
  unsigned int u = __float_as_uint(f);
  unsigned int r = (u + 0x7FFFu + ((u >> 16) & 1u)) >> 16;
  return (unsigned short)r;
}
static __device__ __forceinline__ unsigned short f2bf_fast(float f) {
  return (unsigned short)((__float_as_uint(f) + 0x8000u) >> 16);
}
static __device__ __forceinline__ float bf2f(unsigned short u) {
  return __uint_as_float((unsigned int)u << 16);
}

__device__ __forceinline__ void gload_lds16(const void* g, void* l) {
  __builtin_amdgcn_global_load_lds((const __attribute__((address_space(1))) void*)g,
                                   (__attribute__((address_space(3))) void*)l,
                                   16, 0, 0);
}

// ---------------------------------------------------------------------------
// Fused prep: blocks [0,4096) transpose Wq/Wk/Wv/Wo (1024x1024 each);
// [4096,8192) W1 (1024x4096); [8192,12288) W2 (4096x1024);
// [12288,16384) LayerNorm rows of x.
// ---------------------------------------------------------------------------
__global__ __launch_bounds__(256) void prep_kernel(
    const float* __restrict__ Wq, const float* __restrict__ Wk,
    const float* __restrict__ Wv, const float* __restrict__ Wo,
    const float* __restrict__ W1, const float* __restrict__ W2,
    const float* __restrict__ x, const float* __restrict__ g1,
    const float* __restrict__ be1,
    bf16_t* __restrict__ WqkvT, bf16_t* __restrict__ W1T,
    bf16_t* __restrict__ W2T, bf16_t* __restrict__ xnb) {
  __shared__ float tile[32][33];
  const int bid = blockIdx.x;
  if (bid < 12288) {
    const float* src;
    bf16_t* dst;
    int rows, cols, bx, by;
    if (bid < 4096) {
      const int z = bid >> 10, r = bid & 1023;
      src = (z == 0) ? Wq : (z == 1) ? Wk : (z == 2) ? Wv : Wo;
      dst = WqkvT + (size_t)z * 1048576;
      rows = 1024; cols = 1024;
      bx = (r & 31) * 32; by = (r >> 5) * 32;
    } else if (bid < 8192) {
      const int r = bid - 4096;
      src = W1; dst = W1T; rows = 1024; cols = 4096;
      bx = (r & 127) * 32; by = (r >> 7) * 32;
    } else {
      const int r = bid - 8192;
      src = W2; dst = W2T; rows = 4096; cols = 1024;
      bx = (r & 31) * 32; by = (r >> 5) * 32;
    }
    const int tx = threadIdx.x & 31, ty = threadIdx.x >> 5;
#pragma unroll
    for (int i = 0; i < 32; i += 8)
      tile[ty + i][tx] = src[(size_t)(by + ty + i) * cols + (bx + tx)];
    __syncthreads();
#pragma unroll
    for (int i = 0; i < 32; i += 8)
      dst[(size_t)(bx + ty + i) * rows + (by + tx)] = f2bf(tile[tx][ty + i]);
  } else {
    const int row = bid - 12288;
    const int tid = threadIdx.x;
    const float4 v = reinterpret_cast<const float4*>(x + (size_t)row * 1024)[tid];
    float s = v.x + v.y + v.z + v.w;
    float ss = v.x * v.x + v.y * v.y + v.z * v.z + v.w * v.w;
#pragma unroll
    for (int off = 32; off; off >>= 1) {
      s += __shfl_xor(s, off, 64);
      ss += __shfl_xor(ss, off, 64);
    }
    float* red = &tile[0][0];
    const int wave = tid >> 6, lane = tid & 63;
    if (lane == 0) { red[wave] = s; red[4 + wave] = ss; }
    __syncthreads();
    const float mu = (red[0] + red[1] + red[2] + red[3]) * (1.f / 1024.f);
    const float ms = (red[4] + red[5] + red[6] + red[7]) * (1.f / 1024.f);
    const float rstd = rsqrtf(ms - mu * mu + 1e-5f);
    const float4 gg = reinterpret_cast<const float4*>(g1)[tid];
    const float4 bb = reinterpret_cast<const float4*>(be1)[tid];
    bf16_t* o = xnb + (size_t)row * 1024 + tid * 4;
    o[0] = f2bf((v.x - mu) * rstd * gg.x + bb.x);
    o[1] = f2bf((v.y - mu) * rstd * gg.y + bb.y);
    o[2] = f2bf((v.z - mu) * rstd * gg.z + bb.z);
    o[3] = f2bf((v.w - mu) * rstd * gg.w + bb.w);
  }
}

// ---------------------------------------------------------------------------
// LN2-combine: x2 = sum(4 bf16 partials)+bo+x ; x2 f32 out + xn2 = LN(x2) bf16
// ---------------------------------------------------------------------------
__global__ __launch_bounds__(256) void ln2_combine(const bf16_t* __restrict__ p,
                                                   const float* __restrict__ x,
                                                   const float* __restrict__ bo,
                                                   const float* __restrict__ g,
                                                   const float* __restrict__ be,
                                                   float* __restrict__ x2,
                                                   bf16_t* __restrict__ xn) {
  const int row = blockIdx.x;
  const int tid = threadIdx.x;
  const float4 xv = reinterpret_cast<const float4*>(x + (size_t)row * 1024)[tid];
  const float4 bb = reinterpret_cast<const float4*>(bo)[tid];
  float4 v = {bb.x + xv.x, bb.y + xv.y, bb.z + xv.z, bb.w + xv.w};
#pragma unroll
  for (int z = 0; z < 4; ++z) {
    const ushort4 a = reinterpret_cast<const ushort4*>(p + (size_t)z * 4194304 + (size_t)row * 1024)[tid];
    v.x += bf2f(a.x); v.y += bf2f(a.y); v.z += bf2f(a.z); v.w += bf2f(a.w);
  }
  reinterpret_cast<float4*>(x2 + (size_t)row * 1024)[tid] = v;
  float s = v.x + v.y + v.z + v.w;
  float ss = v.x * v.x + v.y * v.y + v.z * v.z + v.w * v.w;
#pragma unroll
  for (int off = 32; off; off >>= 1) {
    s += __shfl_xor(s, off, 64);
    ss += __shfl_xor(ss, off, 64);
  }
  __shared__ float red[8];
  const int wave = tid >> 6, lane = tid & 63;
  if (lane == 0) { red[wave] = s; red[4 + wave] = ss; }
  __syncthreads();
  const float mu = (red[0] + red[1] + red[2] + red[3]) * (1.f / 1024.f);
  const float ms = (red[4] + red[5] + red[6] + red[7]) * (1.f / 1024.f);
  const float rstd = rsqrtf(ms - mu * mu + 1e-5f);
  const float4 gg = reinterpret_cast<const float4*>(g)[tid];
  const float4 eb = reinterpret_cast<const float4*>(be)[tid];
  bf16_t* o = xn + (size_t)row * 1024 + tid * 4;
  o[0] = f2bf((v.x - mu) * rstd * gg.x + eb.x);
  o[1] = f2bf((v.y - mu) * rstd * gg.y + eb.y);
  o[2] = f2bf((v.z - mu) * rstd * gg.z + eb.z);
  o[3] = f2bf((v.w - mu) * rstd * gg.w + eb.w);
}

// ---------------------------------------------------------------------------
// FFN combine: out = bf(p0)+bf(p1)+bf(p2)+b2+x2
// ---------------------------------------------------------------------------
__global__ __launch_bounds__(256) void ffn_combine(const bf16_t* __restrict__ p0,
                                                   const bf16_t* __restrict__ p2,
                                                   const float* __restrict__ x2,
                                                   const float* __restrict__ b2,
                                                   float* __restrict__ out) {
  const int row = blockIdx.x;
  const int tid = threadIdx.x;
  const ushort4 a0 = reinterpret_cast<const ushort4*>(p0 + (size_t)row * 1024)[tid];
  const ushort4 a1 = reinterpret_cast<const ushort4*>(p0 + 4194304 + (size_t)row * 1024)[tid];
  const ushort4 a2 = reinterpret_cast<const ushort4*>(p2 + (size_t)row * 1024)[tid];
  const float4 xv = reinterpret_cast<const float4*>(x2 + (size_t)row * 1024)[tid];
  const float4 bb = reinterpret_cast<const float4*>(b2)[tid];
  float4 v;
  v.x = bf2f(a0.x) + bf2f(a1.x) + bf2f(a2.x) + bb.x + xv.x;
  v.y = bf2f(a0.y) + bf2f(a1.y) + bf2f(a2.y) + bb.y + xv.y;
  v.z = bf2f(a0.z) + bf2f(a1.z) + bf2f(a2.z) + bb.z + xv.z;
  v.w = bf2f(a0.w) + bf2f(a1.w) + bf2f(a2.w) + bb.w + xv.w;
  reinterpret_cast<float4*>(out + (size_t)row * 1024)[tid] = v;
}

// ---------------------------------------------------------------------------
// RoPE in place on bf16 q,k [B,H,S,64]; q scaled by (1/8)*log2(e) so the
// attention softmax can use exp2 directly.
// ---------------------------------------------------------------------------
__global__ __launch_bounds__(256) void rope_bf16(bf16_t* __restrict__ q,
                                                 bf16_t* __restrict__ k) {
  const int id = blockIdx.x * 256 + threadIdx.x;
  const int i = id & 31;
  const int s = (id >> 5) & 2047;
  const int bh = id >> 16;
  const float inv = exp2f((float)i * -0.41524101186f);
  float sn, cs;
  sincosf((float)s * inv, &sn, &cs);
  const size_t base = ((size_t)bh * 2048 + s) * 64 + 2 * i;
  unsigned int qp = *(unsigned int*)&q[base];
  unsigned int kp = *(unsigned int*)&k[base];
  const float q0 = bf2f(qp & 0xffff), q1 = bf2f(qp >> 16);
  const float k0 = bf2f(kp & 0xffff), k1 = bf2f(kp >> 16);
  const float qs = 0.18033688f;  // 0.125 * log2(e)
  const unsigned int qo =
      (unsigned int)f2bf((q0 * cs - q1 * sn) * qs) |
      ((unsigned int)f2bf((q0 * sn + q1 * cs) * qs) << 16);
  const unsigned int ko =
      (unsigned int)f2bf(k0 * cs - k1 * sn) |
      ((unsigned int)f2bf(k0 * sn + k1 * cs) << 16);
  *(unsigned int*)&q[base] = qo;
  *(unsigned int*)&k[base] = ko;
}

// ---------------------------------------------------------------------------
// MFMA flash attention, software-pipelined with double-buffered P tile.
// grid (32 bh, 32), block 256 = 4 waves: qsub=wave&1 (32 q rows), kh=wave>>1
// (1024-K half). Per iter: read P(it) from buf A, K(it+1) loads + QK MFMAs,
// V(it) loads, PV(it) MFMAs, exp(it+1) -> buf B. exp chain overlaps PV MFMAs.
// No barriers in main loop. End: LDS merge of the 2 K-halves (R3 scheme).
// ---------------------------------------------------------------------------
__global__ __launch_bounds__(256) void attn2p(const bf16_t* __restrict__ qb,
                                              const bf16_t* __restrict__ kb,
                                              const bf16_t* __restrict__ vt,
                                              bf16_t* __restrict__ out) {
  const int bh = blockIdx.x;
  const int tid = threadIdx.x, wave = tid >> 6, lane = tid & 63;
  const int col = lane & 15, quad = lane >> 4;
  const int qsub = wave & 1, kh = wave >> 1;
  const int q0 = blockIdx.y * 64 + qsub * 32;
  const size_t kvb = (size_t)bh * (2048 * 64);

  // psw: 4 waves x 2 bufs x 32x72 bf16 = 36864 B. combine reuses (20992 B).
  __shared__ __align__(16) char smem[36864];
  bf16_t* psw = (bf16_t*)smem + wave * (2 * 2304);

  short8 qf[2][2];
#pragma unroll
  for (int mi = 0; mi < 2; ++mi)
#pragma unroll
    for (int ks = 0; ks < 2; ++ks)
      qf[mi][ks] = *(const short8*)&qb[kvb + (size_t)(q0 + mi * 16 + col) * 64 + ks * 32 + quad * 8];

  f32x4 acc[2][4];
  float lsum[2][4];
#pragma unroll
  for (int mi = 0; mi < 2; ++mi)
#pragma unroll
    for (int n = 0; n < 4; ++n) acc[mi][n] = (f32x4){0.f, 0.f, 0.f, 0.f};
#pragma unroll
  for (int mi = 0; mi < 2; ++mi)
#pragma unroll
    for (int r = 0; r < 4; ++r) lsum[mi][r] = 0.f;

  // prologue: scores for it=0 -> psw buf 0
  {
    const int t = kh * 1024;
    f32x4 sc[2][4];
#pragma unroll
    for (int mi = 0; mi < 2; ++mi)
#pragma unroll
      for (int n = 0; n < 4; ++n) sc[mi][n] = (f32x4){0.f, 0.f, 0.f, 0.f};
#pragma unroll
    for (int ks = 0; ks < 2; ++ks) {
      short8 kf[4];
#pragma unroll
      for (int n = 0; n < 4; ++n)
        kf[n] = *(const short8*)&kb[kvb + (size_t)(t + n * 16 + col) * 64 + ks * 32 + quad * 8];
#pragma unroll
      for (int mi = 0; mi < 2; ++mi)
#pragma unroll
        for (int n = 0; n < 4; ++n)
          sc[mi][n] = __builtin_amdgcn_mfma_f32_16x16x32_bf16(qf[mi][ks], kf[n], sc[mi][n], 0, 0, 0);
    }
#pragma unroll
    for (int mi = 0; mi < 2; ++mi)
#pragma unroll
      for (int n = 0; n < 4; ++n)
#pragma unroll
        for (int r = 0; r < 4; ++r) {
          const float pv = exp2f(sc[mi][n][r]);
          lsum[mi][r] += pv;
          psw[(mi * 16 + quad * 4 + r) * 72 + n * 16 + col] = f2bf_fast(pv);
        }
  }

  for (int it = 0; it < 15; ++it) {
    const int t = kh * 1024 + it * 64;
    bf16_t* prd = psw + (it & 1) * 2304;
    bf16_t* pwr = psw + ((it + 1) & 1) * 2304;
    // P(it) from LDS (frees read buffer)
    short8 pf[2][2];
#pragma unroll
    for (int mi = 0; mi < 2; ++mi)
#pragma unroll
      for (int ks = 0; ks < 2; ++ks)
        pf[mi][ks] = *(const short8*)&prd[(mi * 16 + col) * 72 + ks * 32 + quad * 8];
    // K(it+1) + V(it) loads issued together
    short8 kf[2][4], vf[2][4];
#pragma unroll
    for (int ks = 0; ks < 2; ++ks)
#pragma unroll
      for (int n = 0; n < 4; ++n) {
        kf[ks][n] = *(const short8*)&kb[kvb + (size_t)(t + 64 + n * 16 + col) * 64 + ks * 32 + quad * 8];
        vf[ks][n] = *(const short8*)&vt[kvb + (size_t)(n * 16 + col) * 2048 + t + ks * 32 + quad * 8];
      }
    // QK(it+1)
    f32x4 sc[2][4];
#pragma unroll
    for (int mi = 0; mi < 2; ++mi)
#pragma unroll
      for (int n = 0; n < 4; ++n) sc[mi][n] = (f32x4){0.f, 0.f, 0.f, 0.f};
#pragma unroll
    for (int ks = 0; ks < 2; ++ks)
#pragma unroll
      for (int mi = 0; mi < 2; ++mi)
#pragma unroll
        for (int n = 0; n < 4; ++n)
          sc[mi][n] = __builtin_amdgcn_mfma_f32_16x16x32_bf16(qf[mi][ks], kf[ks][n], sc[mi][n], 0, 0, 0);
    // PV(it) — independent of sc chain; overlaps exp below
#pragma unroll
    for (int ks = 0; ks < 2; ++ks)
#pragma unroll
      for (int mi = 0; mi < 2; ++mi)
#pragma unroll
        for (int n = 0; n < 4; ++n)
          acc[mi][n] = __builtin_amdgcn_mfma_f32_16x16x32_bf16(pf[mi][ks], vf[ks][n], acc[mi][n], 0, 0, 0);
    // exp(it+1) -> write buffer
#pragma unroll
    for (int mi = 0; mi < 2; ++mi)
#pragma unroll
      for (int n = 0; n < 4; ++n)
#pragma unroll
        for (int r = 0; r < 4; ++r) {
          const float pv = exp2f(sc[mi][n][r]);
          lsum[mi][r] += pv;
          pwr[(mi * 16 + quad * 4 + r) * 72 + n * 16 + col] = f2bf_fast(pv);
        }
  }
  // epilogue: PV(15)
  {
    const int t = kh * 1024 + 15 * 64;
    bf16_t* prd = psw + (15 & 1) * 2304;
    short8 pf[2][2];
#pragma unroll
    for (int mi = 0; mi < 2; ++mi)
#pragma unroll
      for (int ks = 0; ks < 2; ++ks)
        pf[mi][ks] = *(const short8*)&prd[(mi * 16 + col) * 72 + ks * 32 + quad * 8];
#pragma unroll
    for (int ks = 0; ks < 2; ++ks) {
      short8 vf[4];
#pragma unroll
      for (int n = 0; n < 4; ++n)
        vf[n] = *(const short8*)&vt[kvb + (size_t)(n * 16 + col) * 2048 + t + ks * 32 + quad * 8];
#pragma unroll
      for (int mi = 0; mi < 2; ++mi)
#pragma unroll
        for (int n = 0; n < 4; ++n)
          acc[mi][n] = __builtin_amdgcn_mfma_f32_16x16x32_bf16(pf[mi][ks], vf[n], acc[mi][n], 0, 0, 0);
    }
  }

  __syncthreads();  // all psw traffic done; smem reused as combine buffer
  float* cmb = (float*)smem;
  if (kh == 1) {
    float* w = cmb + (qsub * 64 + lane) * 41;
#pragma unroll
    for (int mi = 0; mi < 2; ++mi)
#pragma unroll
      for (int n = 0; n < 4; ++n)
#pragma unroll
        for (int r = 0; r < 4; ++r) w[mi * 16 + n * 4 + r] = acc[mi][n][r];
#pragma unroll
    for (int mi = 0; mi < 2; ++mi)
#pragma unroll
      for (int r = 0; r < 4; ++r) w[32 + mi * 4 + r] = lsum[mi][r];
  }
  __syncthreads();
  if (kh == 0) {
    const float* w = cmb + (qsub * 64 + lane) * 41;
#pragma unroll
    for (int mi = 0; mi < 2; ++mi)
#pragma unroll
      for (int n = 0; n < 4; ++n)
#pragma unroll
        for (int r = 0; r < 4; ++r) acc[mi][n][r] += w[mi * 16 + n * 4 + r];
#pragma unroll
    for (int mi = 0; mi < 2; ++mi)
#pragma unroll
      for (int r = 0; r < 4; ++r) {
        float s = lsum[mi][r] + w[32 + mi * 4 + r];
        s += __shfl_xor(s, 1, 64);
        s += __shfl_xor(s, 2, 64);
        s += __shfl_xor(s, 4, 64);
        s += __shfl_xor(s, 8, 64);
        lsum[mi][r] = 1.f / s;
      }
    const int b = bh >> 4, h = bh & 15;
#pragma unroll
    for (int mi = 0; mi < 2; ++mi)
#pragma unroll
      for (int r = 0; r < 4; ++r) {
        const size_t ro = (size_t)(b * 2048 + q0 + mi * 16 + quad * 4 + r) * 1024 + h * 64;
        const float rl = lsum[mi][r];
#pragma unroll
        for (int n = 0; n < 4; ++n) out[ro + n * 16 + col] = f2bf(acc[mi][n][r] * rl);
      }
  }
}

// ---------------------------------------------------------------------------
// bf16 MFMA GEMM, C = A[M][K] @ BT[N][K]^T (m97 structure). Epilogue per MODE.
// Split-K via blockIdx.z: k-range [z*kspan, min(z*kspan+kspan, K)).
// MODE_PART dst: z==2 -> ob1, else ob0 + z*4194304.
// ---------------------------------------------------------------------------
enum { MODE_QKV = 0, MODE_FF1 = 1, MODE_PART = 2 };

template <int MODE>
__global__ __launch_bounds__(256) void gemm_bt(
    const bf16_t* __restrict__ A, const bf16_t* __restrict__ BT,
    int M, int N, int K, int kspan,
    const float* __restrict__ bias0, const float* __restrict__ bias1,
    const float* __restrict__ bias2,
    bf16_t* __restrict__ ob0, bf16_t* __restrict__ ob1, bf16_t* __restrict__ ob2) {
  __shared__ __align__(16) bf16_t As[128 * 32];
  __shared__ __align__(16) bf16_t Bs[128 * 32];
  const int tid = threadIdx.x;
  const int wave = tid >> 6, lane = tid & 63;
  const int row16 = lane & 15, quad = lane >> 4;
  const int m0 = blockIdx.x * 128, n0 = blockIdx.y * 128;
  const int wm = (wave & 1) << 6, wn = (wave >> 1) << 6;

  f32x4 acc[4][4];
#pragma unroll
  for (int i = 0; i < 4; ++i)
#pragma unroll
    for (int j = 0; j < 4; ++j) acc[i][j] = (f32x4){0.f, 0.f, 0.f, 0.f};

  const int r0 = tid >> 2;
  const int kc = (tid & 3) << 3;
  const int kb = blockIdx.z * kspan;
  const int kend = (kb + kspan < K) ? kb + kspan : K;

  for (int k0 = kb; k0 < kend; k0 += 32) {
    gload_lds16(A + (size_t)(m0 + r0) * K + k0 + kc, &As[(size_t)tid * 8]);
    gload_lds16(A + (size_t)(m0 + 64 + r0) * K + k0 + kc, &As[((size_t)tid + 256) * 8]);
    gload_lds16(BT + (size_t)(n0 + r0) * K + k0 + kc, &Bs[(size_t)tid * 8]);
    gload_lds16(BT + (size_t)(n0 + 64 + r0) * K + k0 + kc, &Bs[((size_t)tid + 256) * 8]);
    __syncthreads();
    short8 af[4], bfr[4];
#pragma unroll
    for (int mi = 0; mi < 4; ++mi)
      af[mi] = *(const short8*)&As[(wm + mi * 16 + row16) * 32 + quad * 8];
#pragma unroll
    for (int ni = 0; ni < 4; ++ni)
      bfr[ni] = *(const short8*)&Bs[(wn + ni * 16 + row16) * 32 + quad * 8];
#pragma unroll
    for (int mi = 0; mi < 4; ++mi)
#pragma unroll
      for (int ni = 0; ni < 4; ++ni)
        acc[mi][ni] =
            __builtin_amdgcn_mfma_f32_16x16x32_bf16(af[mi], bfr[ni], acc[mi][ni], 0, 0, 0);
    __syncthreads();
  }

#pragma unroll
  for (int mi = 0; mi < 4; ++mi) {
    const int gm_base = m0 + wm + mi * 16 + quad * 4;
#pragma unroll
    for (int ni = 0; ni < 4; ++ni) {
      const int gn = n0 + wn + ni * 16 + row16;
#pragma unroll
      for (int r = 0; r < 4; ++r) {
        const int gm = gm_base + r;
        const float c = acc[mi][ni][r];
        if (MODE == MODE_QKV) {
          const int b = gm >> 11, s = gm & 2047;
          if (gn < 1024) {
            const int h = gn >> 6, d = gn & 63;
            ob0[(((size_t)b * 16 + h) * 2048 + s) * 64 + d] = f2bf(c + bias0[gn]);
          } else if (gn < 2048) {
            const int nn = gn - 1024, h = nn >> 6, d = nn & 63;
            ob1[(((size_t)b * 16 + h) * 2048 + s) * 64 + d] = f2bf(c + bias1[nn]);
          } else {
            const int nn = gn - 2048, h = nn >> 6, d = nn & 63;
            ob2[(((size_t)b * 16 + h) * 64 + d) * 2048 + s] = f2bf(c + bias2[nn]);
          }
        } else if (MODE == MODE_FF1) {
          ob0[(size_t)gm * N + gn] = f2bf(fmaxf(c + bias0[gn], 0.f));
        } else {  // MODE_PART
          bf16_t* dst = (blockIdx.z == 2) ? ob1 : ob0 + (size_t)blockIdx.z * 4194304;
          dst[(size_t)gm * N + gn] = f2bf(c);
        }
      }
    }
  }
}

// ---------------------------------------------------------------------------
extern "C" void kernel_launch(void* const* d_in, const int* in_sizes, int n_in,
                              void* d_out, int out_size, void* d_ws, size_t ws_size,
                              hipStream_t stream) {
  const float* x = (const float*)d_in[0];
  const float* Wq = (const float*)d_in[1];
  const float* bq = (const float*)d_in[2];
  const float* Wk = (const float*)d_in[3];
  const float* bk = (const float*)d_in[4];
  const float* Wv = (const float*)d_in[5];
  const float* bv = (const float*)d_in[6];
  const float* Wo = (const float*)d_in[7];
  const float* bo = (const float*)d_in[8];
  const float* W1 = (const float*)d_in[9];
  const float* b1 = (const float*)d_in[10];
  const float* W2 = (const float*)d_in[11];
  const float* b2 = (const float*)d_in[12];
  const float* g1 = (const float*)d_in[13];
  const float* be1 = (const float*)d_in[14];
  const float* g2 = (const float*)d_in[15];
  const float* be2 = (const float*)d_in[16];
  float* out = (float*)d_out;

  char* ws = (char*)d_ws;
  size_t off = 0;
  auto alloc = [&](size_t bytes) {
    void* p = ws + off;
    off += (bytes + 255) & ~(size_t)255;
    return p;
  };
  bf16_t* WqkvT = (bf16_t*)alloc(3072ULL * 1024 * 2);  // [0,6MB)
  bf16_t* WoT = (bf16_t*)alloc(1024ULL * 1024 * 2);    // [6,8)
  bf16_t* W1T = (bf16_t*)alloc(4096ULL * 1024 * 2);    // [8,16)
  bf16_t* W2T = (bf16_t*)alloc(1024ULL * 4096 * 2);    // [16,24)
  bf16_t* xnb = (bf16_t*)alloc(4096ULL * 1024 * 2);    // [24,32) xn1/attn_out/xn2/FF2-partial2
  bf16_t* qb = (bf16_t*)alloc(4194304ULL * 2);         // [32,40)
  bf16_t* kb = (bf16_t*)alloc(4194304ULL * 2);         // [40,48)
  bf16_t* vt = (bf16_t*)alloc(4194304ULL * 2);         // [48,56)
  (void)alloc(8ULL << 20);                             // [56,64) tail for h1/x2p
  bf16_t* h1 = qb;       // FF1 out [4096][4096] bf16 over [32,64)
  bf16_t* x2p = qb;      // X2 bf16 partials (4 x 8MB) over [32,64), pre-FF1
  bf16_t* ffp = WqkvT;   // FF2 partials 0,1 over dead weights [0,16)
  float* x2 = (float*)alloc(16777216ULL);              // [64,80)

  // fused transposes + LN1
  prep_kernel<<<16384, 256, 0, stream>>>(Wq, Wk, Wv, Wo, W1, W2, x, g1, be1,
                                         WqkvT, W1T, W2T, xnb);

  gemm_bt<MODE_QKV><<<dim3(32, 24, 1), 256, 0, stream>>>(xnb, WqkvT, 4096, 3072, 1024, 1024,
                                                         bq, bk, bv, qb, kb, vt);

  rope_bf16<<<8192, 256, 0, stream>>>(qb, kb);

  attn2p<<<dim3(32, 32), 256, 0, stream>>>(qb, kb, vt, xnb);

  // X2 = attn_out @ Wo, split-K=4 -> bf16 partials over dead q/k/v/tail
  gemm_bt<MODE_PART><<<dim3(32, 8, 4), 256, 0, stream>>>(xnb, WoT, 4096, 1024, 1024, 256,
                                                         nullptr, nullptr, nullptr,
                                                         x2p, x2p + 2 * 4194304, nullptr);

  // x2 = sum(partials)+bo+x ; xn2 = LN(x2)
  ln2_combine<<<4096, 256, 0, stream>>>(x2p, x, bo, g2, be2, x2, xnb);

  gemm_bt<MODE_FF1><<<dim3(32, 32, 1), 256, 0, stream>>>(xnb, W1T, 4096, 4096, 1024, 1024,
                                                         b1, nullptr, nullptr,
                                                         h1, nullptr, nullptr);

  // FF2 = h1 @ W2, split-K=3 (1376/1376/1344): partials 0,1 over dead weights,
  // partial 2 over dead xnb
  gemm_bt<MODE_PART><<<dim3(32, 8, 3), 256, 0, stream>>>(h1, W2T, 4096, 1024, 4096, 1376,
                                                         nullptr, nullptr, nullptr,
                                                         ffp, xnb, nullptr);

  // out = p0+p1+p2+b2+x2
  ffn_combine<<<4096, 256, 0, stream>>>(ffp, xnb, x2, b2, out);
}

// Round 7
// 426.141 us; speedup vs baseline: 1.6145x; 1.1180x over previous
//
#include <hip/hip_runtime.h>

typedef unsigned short bf16_t;
typedef short short8 __attribute__((ext_vector_type(8)));
typedef float f32x4 __attribute__((ext_vector_type(4)));

static __device__ __forceinline__ unsigned short f2bf(float f) {
  unsigned int u = __float_as_uint(f);
  unsigned int r = (u + 0x7FFFu + ((u >> 16) & 1u)) >> 16;
  return (unsigned short)r;
}
static __device__ __forceinline__ unsigned short f2bf_fast(float f) {
  return (unsigned short)((__float_as_uint(f) + 0x8000u) >> 16);
}
static __device__ __forceinline__ float bf2f(unsigned short u) {
  return __uint_as_float((unsigned int)u << 16);
}

__device__ __forceinline__ void gload_lds16(const void* g, void* l) {
  __builtin_amdgcn_global_load_lds((const __attribute__((address_space(1))) void*)g,
                                   (__attribute__((address_space(3))) void*)l,
                                   16, 0, 0);
}

// ---------------------------------------------------------------------------
// Fused prep: blocks [0,4096) transpose Wq/Wk/Wv/Wo (1024x1024 each);
// [4096,8192) W1 (1024x4096); [8192,12288) W2 (4096x1024);
// [12288,16384) LayerNorm rows of x.
// ---------------------------------------------------------------------------
__global__ __launch_bounds__(256) void prep_kernel(
    const float* __restrict__ Wq, const float* __restrict__ Wk,
    const float* __restrict__ Wv, const float* __restrict__ Wo,
    const float* __restrict__ W1, const float* __restrict__ W2,
    const float* __restrict__ x, const float* __restrict__ g1,
    const float* __restrict__ be1,
    bf16_t* __restrict__ WqkvT, bf16_t* __restrict__ W1T,
    bf16_t* __restrict__ W2T, bf16_t* __restrict__ xnb) {
  __shared__ float tile[32][33];
  const int bid = blockIdx.x;
  if (bid < 12288) {
    const float* src;
    bf16_t* dst;
    int rows, cols, bx, by;
    if (bid < 4096) {
      const int z = bid >> 10, r = bid & 1023;
      src = (z == 0) ? Wq : (z == 1) ? Wk : (z == 2) ? Wv : Wo;
      dst = WqkvT + (size_t)z * 1048576;
      rows = 1024; cols = 1024;
      bx = (r & 31) * 32; by = (r >> 5) * 32;
    } else if (bid < 8192) {
      const int r = bid - 4096;
      src = W1; dst = W1T; rows = 1024; cols = 4096;
      bx = (r & 127) * 32; by = (r >> 7) * 32;
    } else {
      const int r = bid - 8192;
      src = W2; dst = W2T; rows = 4096; cols = 1024;
      bx = (r & 31) * 32; by = (r >> 5) * 32;
    }
    const int tx = threadIdx.x & 31, ty = threadIdx.x >> 5;
#pragma unroll
    for (int i = 0; i < 32; i += 8)
      tile[ty + i][tx] = src[(size_t)(by + ty + i) * cols + (bx + tx)];
    __syncthreads();
#pragma unroll
    for (int i = 0; i < 32; i += 8)
      dst[(size_t)(bx + ty + i) * rows + (by + tx)] = f2bf(tile[tx][ty + i]);
  } else {
    const int row = bid - 12288;
    const int tid = threadIdx.x;
    const float4 v = reinterpret_cast<const float4*>(x + (size_t)row * 1024)[tid];
    float s = v.x + v.y + v.z + v.w;
    float ss = v.x * v.x + v.y * v.y + v.z * v.z + v.w * v.w;
#pragma unroll
    for (int off = 32; off; off >>= 1) {
      s += __shfl_xor(s, off, 64);
      ss += __shfl_xor(ss, off, 64);
    }
    float* red = &tile[0][0];
    const int wave = tid >> 6, lane = tid & 63;
    if (lane == 0) { red[wave] = s; red[4 + wave] = ss; }
    __syncthreads();
    const float mu = (red[0] + red[1] + red[2] + red[3]) * (1.f / 1024.f);
    const float ms = (red[4] + red[5] + red[6] + red[7]) * (1.f / 1024.f);
    const float rstd = rsqrtf(ms - mu * mu + 1e-5f);
    const float4 gg = reinterpret_cast<const float4*>(g1)[tid];
    const float4 bb = reinterpret_cast<const float4*>(be1)[tid];
    bf16_t* o = xnb + (size_t)row * 1024 + tid * 4;
    o[0] = f2bf((v.x - mu) * rstd * gg.x + bb.x);
    o[1] = f2bf((v.y - mu) * rstd * gg.y + bb.y);
    o[2] = f2bf((v.z - mu) * rstd * gg.z + bb.z);
    o[3] = f2bf((v.w - mu) * rstd * gg.w + bb.w);
  }
}

// ---------------------------------------------------------------------------
// LN2-combine: x2 = sum(4 bf16 partials)+bo+x ; x2 f32 out + xn2 = LN(x2) bf16
// ---------------------------------------------------------------------------
__global__ __launch_bounds__(256) void ln2_combine(const bf16_t* __restrict__ p,
                                                   const float* __restrict__ x,
                                                   const float* __restrict__ bo,
                                                   const float* __restrict__ g,
                                                   const float* __restrict__ be,
                                                   float* __restrict__ x2,
                                                   bf16_t* __restrict__ xn) {
  const int row = blockIdx.x;
  const int tid = threadIdx.x;
  const float4 xv = reinterpret_cast<const float4*>(x + (size_t)row * 1024)[tid];
  const float4 bb = reinterpret_cast<const float4*>(bo)[tid];
  float4 v = {bb.x + xv.x, bb.y + xv.y, bb.z + xv.z, bb.w + xv.w};
#pragma unroll
  for (int z = 0; z < 4; ++z) {
    const ushort4 a = reinterpret_cast<const ushort4*>(p + (size_t)z * 4194304 + (size_t)row * 1024)[tid];
    v.x += bf2f(a.x); v.y += bf2f(a.y); v.z += bf2f(a.z); v.w += bf2f(a.w);
  }
  reinterpret_cast<float4*>(x2 + (size_t)row * 1024)[tid] = v;
  float s = v.x + v.y + v.z + v.w;
  float ss = v.x * v.x + v.y * v.y + v.z * v.z + v.w * v.w;
#pragma unroll
  for (int off = 32; off; off >>= 1) {
    s += __shfl_xor(s, off, 64);
    ss += __shfl_xor(ss, off, 64);
  }
  __shared__ float red[8];
  const int wave = tid >> 6, lane = tid & 63;
  if (lane == 0) { red[wave] = s; red[4 + wave] = ss; }
  __syncthreads();
  const float mu = (red[0] + red[1] + red[2] + red[3]) * (1.f / 1024.f);
  const float ms = (red[4] + red[5] + red[6] + red[7]) * (1.f / 1024.f);
  const float rstd = rsqrtf(ms - mu * mu + 1e-5f);
  const float4 gg = reinterpret_cast<const float4*>(g)[tid];
  const float4 eb = reinterpret_cast<const float4*>(be)[tid];
  bf16_t* o = xn + (size_t)row * 1024 + tid * 4;
  o[0] = f2bf((v.x - mu) * rstd * gg.x + eb.x);
  o[1] = f2bf((v.y - mu) * rstd * gg.y + eb.y);
  o[2] = f2bf((v.z - mu) * rstd * gg.z + eb.z);
  o[3] = f2bf((v.w - mu) * rstd * gg.w + eb.w);
}

// ---------------------------------------------------------------------------
// FFN combine: out = bf(p0)+bf(p1)+bf(p2)+b2+x2
// ---------------------------------------------------------------------------
__global__ __launch_bounds__(256) void ffn_combine(const bf16_t* __restrict__ p0,
                                                   const bf16_t* __restrict__ p2,
                                                   const float* __restrict__ x2,
                                                   const float* __restrict__ b2,
                                                   float* __restrict__ out) {
  const int row = blockIdx.x;
  const int tid = threadIdx.x;
  const ushort4 a0 = reinterpret_cast<const ushort4*>(p0 + (size_t)row * 1024)[tid];
  const ushort4 a1 = reinterpret_cast<const ushort4*>(p0 + 4194304 + (size_t)row * 1024)[tid];
  const ushort4 a2 = reinterpret_cast<const ushort4*>(p2 + (size_t)row * 1024)[tid];
  const float4 xv = reinterpret_cast<const float4*>(x2 + (size_t)row * 1024)[tid];
  const float4 bb = reinterpret_cast<const float4*>(b2)[tid];
  float4 v;
  v.x = bf2f(a0.x) + bf2f(a1.x) + bf2f(a2.x) + bb.x + xv.x;
  v.y = bf2f(a0.y) + bf2f(a1.y) + bf2f(a2.y) + bb.y + xv.y;
  v.z = bf2f(a0.z) + bf2f(a1.z) + bf2f(a2.z) + bb.z + xv.z;
  v.w = bf2f(a0.w) + bf2f(a1.w) + bf2f(a2.w) + bb.w + xv.w;
  reinterpret_cast<float4*>(out + (size_t)row * 1024)[tid] = v;
}

// ---------------------------------------------------------------------------
// RoPE in place on bf16 q,k [B,H,S,64]; q scaled by (1/8)*log2(e).
// ---------------------------------------------------------------------------
__global__ __launch_bounds__(256) void rope_bf16(bf16_t* __restrict__ q,
                                                 bf16_t* __restrict__ k) {
  const int id = blockIdx.x * 256 + threadIdx.x;
  const int i = id & 31;
  const int s = (id >> 5) & 2047;
  const int bh = id >> 16;
  const float inv = exp2f((float)i * -0.41524101186f);
  float sn, cs;
  sincosf((float)s * inv, &sn, &cs);
  const size_t base = ((size_t)bh * 2048 + s) * 64 + 2 * i;
  unsigned int qp = *(unsigned int*)&q[base];
  unsigned int kp = *(unsigned int*)&k[base];
  const float q0 = bf2f(qp & 0xffff), q1 = bf2f(qp >> 16);
  const float k0 = bf2f(kp & 0xffff), k1 = bf2f(kp >> 16);
  const float qs = 0.18033688f;  // 0.125 * log2(e)
  const unsigned int qo =
      (unsigned int)f2bf((q0 * cs - q1 * sn) * qs) |
      ((unsigned int)f2bf((q0 * sn + q1 * cs) * qs) << 16);
  const unsigned int ko =
      (unsigned int)f2bf(k0 * cs - k1 * sn) |
      ((unsigned int)f2bf(k0 * sn + k1 * cs) << 16);
  *(unsigned int*)&q[base] = qo;
  *(unsigned int*)&k[base] = ko;
}

// ---------------------------------------------------------------------------
// V transpose: v [b,h,s,64] bf16 -> vt [b,h,64,2048] bf16
// ---------------------------------------------------------------------------
__global__ __launch_bounds__(256) void vtrans(const bf16_t* __restrict__ v,
                                              bf16_t* __restrict__ vt) {
  __shared__ bf16_t tile[32][33];
  const int bh = blockIdx.x;
  const int s0 = blockIdx.y * 32;
  const int d0 = blockIdx.z * 32;
  const int tx = threadIdx.x & 31, ty = threadIdx.x >> 5;
  const size_t base = (size_t)bh * (2048 * 64);
#pragma unroll
  for (int i = 0; i < 32; i += 8)
    tile[ty + i][tx] = v[base + (size_t)(s0 + ty + i) * 64 + d0 + tx];
  __syncthreads();
#pragma unroll
  for (int i = 0; i < 32; i += 8)
    vt[base + (size_t)(d0 + ty + i) * 2048 + s0 + tx] = tile[tx][ty + i];
}

// ---------------------------------------------------------------------------
// Block-cooperative MFMA flash attention. grid (32 bh, 16), block 256 =
// 4 waves, each owning 32 q-rows of a 128-row q-tile; full 2048-K sweep.
// K/V 64-tiles staged ONCE per block into LDS via global_load_lds with
// XOR chunk swizzle (c ^= r&7) for conflict-free frag reads (no padding
// possible: wave-uniform-base constraint). m97 2-barrier loop. No cross-
// wave merge: each wave completes its rows.
// ---------------------------------------------------------------------------
__global__ __launch_bounds__(256) void attn3(const bf16_t* __restrict__ qb,
                                             const bf16_t* __restrict__ kb,
                                             const bf16_t* __restrict__ vt,
                                             bf16_t* __restrict__ out) {
  const int bh = blockIdx.x;
  const int tid = threadIdx.x, wave = tid >> 6, lane = tid & 63;
  const int col = lane & 15, quad = lane >> 4;
  const int q0 = blockIdx.y * 128 + wave * 32;
  const size_t kvb = (size_t)bh * (2048 * 64);

  __shared__ __align__(16) bf16_t Ks[4096];           // 64x64, swizzled chunks
  __shared__ __align__(16) bf16_t Vs[4096];
  __shared__ __align__(16) bf16_t psw_all[4 * 32 * 72];
  bf16_t* psw = psw_all + wave * (32 * 72);

  short8 qf[2][2];
#pragma unroll
  for (int mi = 0; mi < 2; ++mi)
#pragma unroll
    for (int ks = 0; ks < 2; ++ks)
      qf[mi][ks] = *(const short8*)&qb[kvb + (size_t)(q0 + mi * 16 + col) * 64 + ks * 32 + quad * 8];

  f32x4 acc[2][4];
  float lsum[2][4];
#pragma unroll
  for (int mi = 0; mi < 2; ++mi)
#pragma unroll
    for (int n = 0; n < 4; ++n) acc[mi][n] = (f32x4){0.f, 0.f, 0.f, 0.f};
#pragma unroll
  for (int mi = 0; mi < 2; ++mi)
#pragma unroll
    for (int r = 0; r < 4; ++r) lsum[mi][r] = 0.f;

  // staging: 512 16B-slots per tile; wave w covers slots [w*128, w*128+128)
  // slot s -> row r = s>>3, chunk c = (s&7) ^ (r&7)
  const int swz = (col & 7);  // frag-read swizzle term (row&7 == col&7)

  for (int t = 0; t < 2048; t += 64) {
#pragma unroll
    for (int j = 0; j < 2; ++j) {
      const int s = wave * 128 + j * 64 + lane;
      const int r = s >> 3;
      const int c = (s & 7) ^ (r & 7);
      gload_lds16(kb + kvb + (size_t)(t + r) * 64 + c * 8, Ks + (size_t)(wave * 128 + j * 64) * 8);
      gload_lds16(vt + kvb + (size_t)r * 2048 + t + c * 8, Vs + (size_t)(wave * 128 + j * 64) * 8);
    }
    __syncthreads();  // drain loads, tiles visible
    // --- scores S[32q][64k] = Q K^T ---
    f32x4 sc[2][4];
#pragma unroll
    for (int mi = 0; mi < 2; ++mi)
#pragma unroll
      for (int n = 0; n < 4; ++n) sc[mi][n] = (f32x4){0.f, 0.f, 0.f, 0.f};
#pragma unroll
    for (int ks = 0; ks < 2; ++ks) {
      short8 kf[4];
#pragma unroll
      for (int n = 0; n < 4; ++n) {
        const int R = n * 16 + col;
        const int C = (ks * 4 + quad) ^ swz;
        kf[n] = *(const short8*)&Ks[(size_t)(R * 8 + C) * 8];
      }
#pragma unroll
      for (int mi = 0; mi < 2; ++mi)
#pragma unroll
        for (int n = 0; n < 4; ++n)
          sc[mi][n] = __builtin_amdgcn_mfma_f32_16x16x32_bf16(qf[mi][ks], kf[n], sc[mi][n], 0, 0, 0);
    }
    // --- exp2 (no max; log2e folded into q), row-partials, P -> psw ---
#pragma unroll
    for (int mi = 0; mi < 2; ++mi)
#pragma unroll
      for (int n = 0; n < 4; ++n)
#pragma unroll
        for (int r = 0; r < 4; ++r) {
          const float pv = exp2f(sc[mi][n][r]);
          lsum[mi][r] += pv;
          psw[(mi * 16 + quad * 4 + r) * 72 + n * 16 + col] = f2bf_fast(pv);
        }
    short8 pf[2][2];
#pragma unroll
    for (int mi = 0; mi < 2; ++mi)
#pragma unroll
      for (int ks = 0; ks < 2; ++ks)
        pf[mi][ks] = *(const short8*)&psw[(mi * 16 + col) * 72 + ks * 32 + quad * 8];
    // --- O += P V ---
#pragma unroll
    for (int ks = 0; ks < 2; ++ks) {
      short8 vf[4];
#pragma unroll
      for (int n = 0; n < 4; ++n) {
        const int R = n * 16 + col;
        const int C = (ks * 4 + quad) ^ swz;
        vf[n] = *(const short8*)&Vs[(size_t)(R * 8 + C) * 8];
      }
#pragma unroll
      for (int mi = 0; mi < 2; ++mi)
#pragma unroll
        for (int n = 0; n < 4; ++n)
          acc[mi][n] = __builtin_amdgcn_mfma_f32_16x16x32_bf16(pf[mi][ks], vf[n], acc[mi][n], 0, 0, 0);
    }
    __syncthreads();  // all reads done before next staging overwrites
  }

  const int b = bh >> 4, h = bh & 15;
#pragma unroll
  for (int mi = 0; mi < 2; ++mi)
#pragma unroll
    for (int r = 0; r < 4; ++r) {
      float s = lsum[mi][r];
      s += __shfl_xor(s, 1, 64);
      s += __shfl_xor(s, 2, 64);
      s += __shfl_xor(s, 4, 64);
      s += __shfl_xor(s, 8, 64);
      const float rl = 1.f / s;
      const size_t ro = (size_t)(b * 2048 + q0 + mi * 16 + quad * 4 + r) * 1024 + h * 64;
#pragma unroll
      for (int n = 0; n < 4; ++n) out[ro + n * 16 + col] = f2bf(acc[mi][n][r] * rl);
    }
}

// ---------------------------------------------------------------------------
// bf16 MFMA GEMM, C = A[M][K] @ BT[N][K]^T (m97 structure). Epilogue per MODE.
// ---------------------------------------------------------------------------
enum { MODE_QKV = 0, MODE_FF1 = 1, MODE_PART = 2 };

template <int MODE>
__global__ __launch_bounds__(256) void gemm_bt(
    const bf16_t* __restrict__ A, const bf16_t* __restrict__ BT,
    int M, int N, int K, int kspan,
    const float* __restrict__ bias0, const float* __restrict__ bias1,
    const float* __restrict__ bias2,
    bf16_t* __restrict__ ob0, bf16_t* __restrict__ ob1, bf16_t* __restrict__ ob2) {
  __shared__ __align__(16) bf16_t As[128 * 32];
  __shared__ __align__(16) bf16_t Bs[128 * 32];
  const int tid = threadIdx.x;
  const int wave = tid >> 6, lane = tid & 63;
  const int row16 = lane & 15, quad = lane >> 4;
  const int m0 = blockIdx.x * 128, n0 = blockIdx.y * 128;
  const int wm = (wave & 1) << 6, wn = (wave >> 1) << 6;

  f32x4 acc[4][4];
#pragma unroll
  for (int i = 0; i < 4; ++i)
#pragma unroll
    for (int j = 0; j < 4; ++j) acc[i][j] = (f32x4){0.f, 0.f, 0.f, 0.f};

  const int r0 = tid >> 2;
  const int kc = (tid & 3) << 3;
  const int kb = blockIdx.z * kspan;
  const int kend = (kb + kspan < K) ? kb + kspan : K;

  for (int k0 = kb; k0 < kend; k0 += 32) {
    gload_lds16(A + (size_t)(m0 + r0) * K + k0 + kc, &As[(size_t)tid * 8]);
    gload_lds16(A + (size_t)(m0 + 64 + r0) * K + k0 + kc, &As[((size_t)tid + 256) * 8]);
    gload_lds16(BT + (size_t)(n0 + r0) * K + k0 + kc, &Bs[(size_t)tid * 8]);
    gload_lds16(BT + (size_t)(n0 + 64 + r0) * K + k0 + kc, &Bs[((size_t)tid + 256) * 8]);
    __syncthreads();
    short8 af[4], bfr[4];
#pragma unroll
    for (int mi = 0; mi < 4; ++mi)
      af[mi] = *(const short8*)&As[(wm + mi * 16 + row16) * 32 + quad * 8];
#pragma unroll
    for (int ni = 0; ni < 4; ++ni)
      bfr[ni] = *(const short8*)&Bs[(wn + ni * 16 + row16) * 32 + quad * 8];
#pragma unroll
    for (int mi = 0; mi < 4; ++mi)
#pragma unroll
      for (int ni = 0; ni < 4; ++ni)
        acc[mi][ni] =
            __builtin_amdgcn_mfma_f32_16x16x32_bf16(af[mi], bfr[ni], acc[mi][ni], 0, 0, 0);
    __syncthreads();
  }

#pragma unroll
  for (int mi = 0; mi < 4; ++mi) {
    const int gm_base = m0 + wm + mi * 16 + quad * 4;
#pragma unroll
    for (int ni = 0; ni < 4; ++ni) {
      const int gn = n0 + wn + ni * 16 + row16;
#pragma unroll
      for (int r = 0; r < 4; ++r) {
        const int gm = gm_base + r;
        const float c = acc[mi][ni][r];
        if (MODE == MODE_QKV) {
          const int b = gm >> 11, s = gm & 2047;
          if (gn < 1024) {
            const int h = gn >> 6, d = gn & 63;
            ob0[(((size_t)b * 16 + h) * 2048 + s) * 64 + d] = f2bf(c + bias0[gn]);
          } else if (gn < 2048) {
            const int nn = gn - 1024, h = nn >> 6, d = nn & 63;
            ob1[(((size_t)b * 16 + h) * 2048 + s) * 64 + d] = f2bf(c + bias1[nn]);
          } else {
            const int nn = gn - 2048, h = nn >> 6, d = nn & 63;
            ob2[(((size_t)b * 16 + h) * 2048 + s) * 64 + d] = f2bf(c + bias2[nn]);
          }
        } else if (MODE == MODE_FF1) {
          ob0[(size_t)gm * N + gn] = f2bf(fmaxf(c + bias0[gn], 0.f));
        } else {  // MODE_PART
          bf16_t* dst = (blockIdx.z == 2) ? ob1 : ob0 + (size_t)blockIdx.z * 4194304;
          dst[(size_t)gm * N + gn] = f2bf(c);
        }
      }
    }
  }
}

// ---------------------------------------------------------------------------
extern "C" void kernel_launch(void* const* d_in, const int* in_sizes, int n_in,
                              void* d_out, int out_size, void* d_ws, size_t ws_size,
                              hipStream_t stream) {
  const float* x = (const float*)d_in[0];
  const float* Wq = (const float*)d_in[1];
  const float* bq = (const float*)d_in[2];
  const float* Wk = (const float*)d_in[3];
  const float* bk = (const float*)d_in[4];
  const float* Wv = (const float*)d_in[5];
  const float* bv = (const float*)d_in[6];
  const float* Wo = (const float*)d_in[7];
  const float* bo = (const float*)d_in[8];
  const float* W1 = (const float*)d_in[9];
  const float* b1 = (const float*)d_in[10];
  const float* W2 = (const float*)d_in[11];
  const float* b2 = (const float*)d_in[12];
  const float* g1 = (const float*)d_in[13];
  const float* be1 = (const float*)d_in[14];
  const float* g2 = (const float*)d_in[15];
  const float* be2 = (const float*)d_in[16];
  float* out = (float*)d_out;

  char* ws = (char*)d_ws;
  size_t off = 0;
  auto alloc = [&](size_t bytes) {
    void* p = ws + off;
    off += (bytes + 255) & ~(size_t)255;
    return p;
  };
  bf16_t* WqkvT = (bf16_t*)alloc(3072ULL * 1024 * 2);  // [0,6MB)
  bf16_t* WoT = (bf16_t*)alloc(1024ULL * 1024 * 2);    // [6,8)
  bf16_t* W1T = (bf16_t*)alloc(4096ULL * 1024 * 2);    // [8,16)
  bf16_t* W2T = (bf16_t*)alloc(1024ULL * 4096 * 2);    // [16,24)
  bf16_t* xnb = (bf16_t*)alloc(4096ULL * 1024 * 2);    // [24,32) xn1/attn_out/xn2/FF2-partial2
  bf16_t* qb = (bf16_t*)alloc(4194304ULL * 2);         // [32,40)
  bf16_t* kb = (bf16_t*)alloc(4194304ULL * 2);         // [40,48)
  bf16_t* vraw = (bf16_t*)alloc(4194304ULL * 2);       // [48,56) V [b,h,s,d]
  bf16_t* vt = (bf16_t*)alloc(4194304ULL * 2);         // [56,64) V^T [b,h,d,s]
  bf16_t* h1 = qb;       // FF1 out [4096][4096] bf16 over [32,64)
  bf16_t* x2p = qb;      // X2 bf16 partials (4 x 8MB) over [32,64), pre-FF1
  bf16_t* ffp = WqkvT;   // FF2 partials 0,1 over dead weights [0,16)
  float* x2 = (float*)alloc(16777216ULL);              // [64,80)

  // fused transposes + LN1
  prep_kernel<<<16384, 256, 0, stream>>>(Wq, Wk, Wv, Wo, W1, W2, x, g1, be1,
                                         WqkvT, W1T, W2T, xnb);

  gemm_bt<MODE_QKV><<<dim3(32, 24, 1), 256, 0, stream>>>(xnb, WqkvT, 4096, 3072, 1024, 1024,
                                                         bq, bk, bv, qb, kb, vraw);

  rope_bf16<<<8192, 256, 0, stream>>>(qb, kb);

  vtrans<<<dim3(32, 64, 2), 256, 0, stream>>>(vraw, vt);

  attn3<<<dim3(32, 16), 256, 0, stream>>>(qb, kb, vt, xnb);

  // X2 = attn_out @ Wo, split-K=4 -> bf16 partials over dead q/k/v buffers
  gemm_bt<MODE_PART><<<dim3(32, 8, 4), 256, 0, stream>>>(xnb, WoT, 4096, 1024, 1024, 256,
                                                         nullptr, nullptr, nullptr,
                                                         x2p, x2p + 2 * 4194304, nullptr);

  // x2 = sum(partials)+bo+x ; xn2 = LN(x2)
  ln2_combine<<<4096, 256, 0, stream>>>(x2p, x, bo, g2, be2, x2, xnb);

  gemm_bt<MODE_FF1><<<dim3(32, 32, 1), 256, 0, stream>>>(xnb, W1T, 4096, 4096, 1024, 1024,
                                                         b1, nullptr, nullptr,
                                                         h1, nullptr, nullptr);

  // FF2 = h1 @ W2, split-K=3 (1376/1376/1344)
  gemm_bt<MODE_PART><<<dim3(32, 8, 3), 256, 0, stream>>>(h1, W2T, 4096, 1024, 4096, 1376,
                                                         nullptr, nullptr, nullptr,
                                                         ffp, xnb, nullptr);

  // out = p0+p1+p2+b2+x2
  ffn_combine<<<4096, 256, 0, stream>>>(ffp, xnb, x2, b2, out);
}

// Round 8
// 366.382 us; speedup vs baseline: 1.8779x; 1.1631x over previous
//
#include <hip/hip_runtime.h>

typedef unsigned short bf16_t;
typedef short short8 __attribute__((ext_vector_type(8)));
typedef float f32x4 __attribute__((ext_vector_type(4)));

static __device__ __forceinline__ unsigned short f2bf(float f) {
  unsigned int u = __float_as_uint(f);
  unsigned int r = (u + 0x7FFFu + ((u >> 16) & 1u)) >> 16;
  return (unsigned short)r;
}
static __device__ __forceinline__ unsigned short f2bf_fast(float f) {
  return (unsigned short)((__float_as_uint(f) + 0x8000u) >> 16);
}
static __device__ __forceinline__ float bf2f(unsigned short u) {
  return __uint_as_float((unsigned int)u << 16);
}

__device__ __forceinline__ void gload_lds16(const void* g, void* l) {
  __builtin_amdgcn_global_load_lds((const __attribute__((address_space(1))) void*)g,
                                   (__attribute__((address_space(3))) void*)l,
                                   16, 0, 0);
}

// ---------------------------------------------------------------------------
// Fused prep: blocks [0,4096) transpose Wq/Wk/Wv/Wo (1024x1024 each);
// [4096,8192) W1 (1024x4096); [8192,12288) W2 (4096x1024);
// [12288,16384) LayerNorm rows of x.
// ---------------------------------------------------------------------------
__global__ __launch_bounds__(256) void prep_kernel(
    const float* __restrict__ Wq, const float* __restrict__ Wk,
    const float* __restrict__ Wv, const float* __restrict__ Wo,
    const float* __restrict__ W1, const float* __restrict__ W2,
    const float* __restrict__ x, const float* __restrict__ g1,
    const float* __restrict__ be1,
    bf16_t* __restrict__ WqkvT, bf16_t* __restrict__ W1T,
    bf16_t* __restrict__ W2T, bf16_t* __restrict__ xnb) {
  __shared__ float tile[32][33];
  const int bid = blockIdx.x;
  if (bid < 12288) {
    const float* src;
    bf16_t* dst;
    int rows, cols, bx, by;
    if (bid < 4096) {
      const int z = bid >> 10, r = bid & 1023;
      src = (z == 0) ? Wq : (z == 1) ? Wk : (z == 2) ? Wv : Wo;
      dst = WqkvT + (size_t)z * 1048576;
      rows = 1024; cols = 1024;
      bx = (r & 31) * 32; by = (r >> 5) * 32;
    } else if (bid < 8192) {
      const int r = bid - 4096;
      src = W1; dst = W1T; rows = 1024; cols = 4096;
      bx = (r & 127) * 32; by = (r >> 7) * 32;
    } else {
      const int r = bid - 8192;
      src = W2; dst = W2T; rows = 4096; cols = 1024;
      bx = (r & 31) * 32; by = (r >> 5) * 32;
    }
    const int tx = threadIdx.x & 31, ty = threadIdx.x >> 5;
#pragma unroll
    for (int i = 0; i < 32; i += 8)
      tile[ty + i][tx] = src[(size_t)(by + ty + i) * cols + (bx + tx)];
    __syncthreads();
#pragma unroll
    for (int i = 0; i < 32; i += 8)
      dst[(size_t)(bx + ty + i) * rows + (by + tx)] = f2bf(tile[tx][ty + i]);
  } else {
    const int row = bid - 12288;
    const int tid = threadIdx.x;
    const float4 v = reinterpret_cast<const float4*>(x + (size_t)row * 1024)[tid];
    float s = v.x + v.y + v.z + v.w;
    float ss = v.x * v.x + v.y * v.y + v.z * v.z + v.w * v.w;
#pragma unroll
    for (int off = 32; off; off >>= 1) {
      s += __shfl_xor(s, off, 64);
      ss += __shfl_xor(ss, off, 64);
    }
    float* red = &tile[0][0];
    const int wave = tid >> 6, lane = tid & 63;
    if (lane == 0) { red[wave] = s; red[4 + wave] = ss; }
    __syncthreads();
    const float mu = (red[0] + red[1] + red[2] + red[3]) * (1.f / 1024.f);
    const float ms = (red[4] + red[5] + red[6] + red[7]) * (1.f / 1024.f);
    const float rstd = rsqrtf(ms - mu * mu + 1e-5f);
    const float4 gg = reinterpret_cast<const float4*>(g1)[tid];
    const float4 bb = reinterpret_cast<const float4*>(be1)[tid];
    bf16_t* o = xnb + (size_t)row * 1024 + tid * 4;
    o[0] = f2bf((v.x - mu) * rstd * gg.x + bb.x);
    o[1] = f2bf((v.y - mu) * rstd * gg.y + bb.y);
    o[2] = f2bf((v.z - mu) * rstd * gg.z + bb.z);
    o[3] = f2bf((v.w - mu) * rstd * gg.w + bb.w);
  }
}

// ---------------------------------------------------------------------------
// LN2-combine: x2 = sum(4 bf16 partials)+bo+x ; x2 f32 out + xn2 = LN(x2) bf16
// ---------------------------------------------------------------------------
__global__ __launch_bounds__(256) void ln2_combine(const bf16_t* __restrict__ p,
                                                   const float* __restrict__ x,
                                                   const float* __restrict__ bo,
                                                   const float* __restrict__ g,
                                                   const float* __restrict__ be,
                                                   float* __restrict__ x2,
                                                   bf16_t* __restrict__ xn) {
  const int row = blockIdx.x;
  const int tid = threadIdx.x;
  const float4 xv = reinterpret_cast<const float4*>(x + (size_t)row * 1024)[tid];
  const float4 bb = reinterpret_cast<const float4*>(bo)[tid];
  float4 v = {bb.x + xv.x, bb.y + xv.y, bb.z + xv.z, bb.w + xv.w};
#pragma unroll
  for (int z = 0; z < 4; ++z) {
    const ushort4 a = reinterpret_cast<const ushort4*>(p + (size_t)z * 4194304 + (size_t)row * 1024)[tid];
    v.x += bf2f(a.x); v.y += bf2f(a.y); v.z += bf2f(a.z); v.w += bf2f(a.w);
  }
  reinterpret_cast<float4*>(x2 + (size_t)row * 1024)[tid] = v;
  float s = v.x + v.y + v.z + v.w;
  float ss = v.x * v.x + v.y * v.y + v.z * v.z + v.w * v.w;
#pragma unroll
  for (int off = 32; off; off >>= 1) {
    s += __shfl_xor(s, off, 64);
    ss += __shfl_xor(ss, off, 64);
  }
  __shared__ float red[8];
  const int wave = tid >> 6, lane = tid & 63;
  if (lane == 0) { red[wave] = s; red[4 + wave] = ss; }
  __syncthreads();
  const float mu = (red[0] + red[1] + red[2] + red[3]) * (1.f / 1024.f);
  const float ms = (red[4] + red[5] + red[6] + red[7]) * (1.f / 1024.f);
  const float rstd = rsqrtf(ms - mu * mu + 1e-5f);
  const float4 gg = reinterpret_cast<const float4*>(g)[tid];
  const float4 eb = reinterpret_cast<const float4*>(be)[tid];
  bf16_t* o = xn + (size_t)row * 1024 + tid * 4;
  o[0] = f2bf((v.x - mu) * rstd * gg.x + eb.x);
  o[1] = f2bf((v.y - mu) * rstd * gg.y + eb.y);
  o[2] = f2bf((v.z - mu) * rstd * gg.z + eb.z);
  o[3] = f2bf((v.w - mu) * rstd * gg.w + eb.w);
}

// ---------------------------------------------------------------------------
// FFN combine: out = bf(p0)+bf(p1)+bf(p2)+b2+x2
// ---------------------------------------------------------------------------
__global__ __launch_bounds__(256) void ffn_combine(const bf16_t* __restrict__ p0,
                                                   const bf16_t* __restrict__ p2,
                                                   const float* __restrict__ x2,
                                                   const float* __restrict__ b2,
                                                   float* __restrict__ out) {
  const int row = blockIdx.x;
  const int tid = threadIdx.x;
  const ushort4 a0 = reinterpret_cast<const ushort4*>(p0 + (size_t)row * 1024)[tid];
  const ushort4 a1 = reinterpret_cast<const ushort4*>(p0 + 4194304 + (size_t)row * 1024)[tid];
  const ushort4 a2 = reinterpret_cast<const ushort4*>(p2 + (size_t)row * 1024)[tid];
  const float4 xv = reinterpret_cast<const float4*>(x2 + (size_t)row * 1024)[tid];
  const float4 bb = reinterpret_cast<const float4*>(b2)[tid];
  float4 v;
  v.x = bf2f(a0.x) + bf2f(a1.x) + bf2f(a2.x) + bb.x + xv.x;
  v.y = bf2f(a0.y) + bf2f(a1.y) + bf2f(a2.y) + bb.y + xv.y;
  v.z = bf2f(a0.z) + bf2f(a1.z) + bf2f(a2.z) + bb.z + xv.z;
  v.w = bf2f(a0.w) + bf2f(a1.w) + bf2f(a2.w) + bb.w + xv.w;
  reinterpret_cast<float4*>(out + (size_t)row * 1024)[tid] = v;
}

// ---------------------------------------------------------------------------
// RoPE in place on bf16 q,k [B,H,S,64]; q scaled by (1/8)*log2(e).
// ---------------------------------------------------------------------------
__global__ __launch_bounds__(256) void rope_bf16(bf16_t* __restrict__ q,
                                                 bf16_t* __restrict__ k) {
  const int id = blockIdx.x * 256 + threadIdx.x;
  const int i = id & 31;
  const int s = (id >> 5) & 2047;
  const int bh = id >> 16;
  const float inv = exp2f((float)i * -0.41524101186f);
  float sn, cs;
  sincosf((float)s * inv, &sn, &cs);
  const size_t base = ((size_t)bh * 2048 + s) * 64 + 2 * i;
  unsigned int qp = *(unsigned int*)&q[base];
  unsigned int kp = *(unsigned int*)&k[base];
  const float q0 = bf2f(qp & 0xffff), q1 = bf2f(qp >> 16);
  const float k0 = bf2f(kp & 0xffff), k1 = bf2f(kp >> 16);
  const float qs = 0.18033688f;  // 0.125 * log2(e)
  const unsigned int qo =
      (unsigned int)f2bf((q0 * cs - q1 * sn) * qs) |
      ((unsigned int)f2bf((q0 * sn + q1 * cs) * qs) << 16);
  const unsigned int ko =
      (unsigned int)f2bf(k0 * cs - k1 * sn) |
      ((unsigned int)f2bf(k0 * sn + k1 * cs) << 16);
  *(unsigned int*)&q[base] = qo;
  *(unsigned int*)&k[base] = ko;
}

// ---------------------------------------------------------------------------
// V transpose: v [b,h,s,64] bf16 -> vt [b,h,64,2048] bf16
// ---------------------------------------------------------------------------
__global__ __launch_bounds__(256) void vtrans(const bf16_t* __restrict__ v,
                                              bf16_t* __restrict__ vt) {
  __shared__ bf16_t tile[32][33];
  const int bh = blockIdx.x;
  const int s0 = blockIdx.y * 32;
  const int d0 = blockIdx.z * 32;
  const int tx = threadIdx.x & 31, ty = threadIdx.x >> 5;
  const size_t base = (size_t)bh * (2048 * 64);
#pragma unroll
  for (int i = 0; i < 32; i += 8)
    tile[ty + i][tx] = v[base + (size_t)(s0 + ty + i) * 64 + d0 + tx];
  __syncthreads();
#pragma unroll
  for (int i = 0; i < 32; i += 8)
    vt[base + (size_t)(d0 + ty + i) * 2048 + s0 + tx] = tile[tx][ty + i];
}

// ---------------------------------------------------------------------------
// Block-cooperative MFMA flash attention (unchanged from R7).
// ---------------------------------------------------------------------------
__global__ __launch_bounds__(256) void attn3(const bf16_t* __restrict__ qb,
                                             const bf16_t* __restrict__ kb,
                                             const bf16_t* __restrict__ vt,
                                             bf16_t* __restrict__ out) {
  const int bh = blockIdx.x;
  const int tid = threadIdx.x, wave = tid >> 6, lane = tid & 63;
  const int col = lane & 15, quad = lane >> 4;
  const int q0 = blockIdx.y * 128 + wave * 32;
  const size_t kvb = (size_t)bh * (2048 * 64);

  __shared__ __align__(16) bf16_t Ks[4096];
  __shared__ __align__(16) bf16_t Vs[4096];
  __shared__ __align__(16) bf16_t psw_all[4 * 32 * 72];
  bf16_t* psw = psw_all + wave * (32 * 72);

  short8 qf[2][2];
#pragma unroll
  for (int mi = 0; mi < 2; ++mi)
#pragma unroll
    for (int ks = 0; ks < 2; ++ks)
      qf[mi][ks] = *(const short8*)&qb[kvb + (size_t)(q0 + mi * 16 + col) * 64 + ks * 32 + quad * 8];

  f32x4 acc[2][4];
  float lsum[2][4];
#pragma unroll
  for (int mi = 0; mi < 2; ++mi)
#pragma unroll
    for (int n = 0; n < 4; ++n) acc[mi][n] = (f32x4){0.f, 0.f, 0.f, 0.f};
#pragma unroll
  for (int mi = 0; mi < 2; ++mi)
#pragma unroll
    for (int r = 0; r < 4; ++r) lsum[mi][r] = 0.f;

  const int swz = (col & 7);

  for (int t = 0; t < 2048; t += 64) {
#pragma unroll
    for (int j = 0; j < 2; ++j) {
      const int s = wave * 128 + j * 64 + lane;
      const int r = s >> 3;
      const int c = (s & 7) ^ (r & 7);
      gload_lds16(kb + kvb + (size_t)(t + r) * 64 + c * 8, Ks + (size_t)(wave * 128 + j * 64) * 8);
      gload_lds16(vt + kvb + (size_t)r * 2048 + t + c * 8, Vs + (size_t)(wave * 128 + j * 64) * 8);
    }
    __syncthreads();
    f32x4 sc[2][4];
#pragma unroll
    for (int mi = 0; mi < 2; ++mi)
#pragma unroll
      for (int n = 0; n < 4; ++n) sc[mi][n] = (f32x4){0.f, 0.f, 0.f, 0.f};
#pragma unroll
    for (int ks = 0; ks < 2; ++ks) {
      short8 kf[4];
#pragma unroll
      for (int n = 0; n < 4; ++n) {
        const int R = n * 16 + col;
        const int C = (ks * 4 + quad) ^ swz;
        kf[n] = *(const short8*)&Ks[(size_t)(R * 8 + C) * 8];
      }
#pragma unroll
      for (int mi = 0; mi < 2; ++mi)
#pragma unroll
        for (int n = 0; n < 4; ++n)
          sc[mi][n] = __builtin_amdgcn_mfma_f32_16x16x32_bf16(qf[mi][ks], kf[n], sc[mi][n], 0, 0, 0);
    }
#pragma unroll
    for (int mi = 0; mi < 2; ++mi)
#pragma unroll
      for (int n = 0; n < 4; ++n)
#pragma unroll
        for (int r = 0; r < 4; ++r) {
          const float pv = exp2f(sc[mi][n][r]);
          lsum[mi][r] += pv;
          psw[(mi * 16 + quad * 4 + r) * 72 + n * 16 + col] = f2bf_fast(pv);
        }
    short8 pf[2][2];
#pragma unroll
    for (int mi = 0; mi < 2; ++mi)
#pragma unroll
      for (int ks = 0; ks < 2; ++ks)
        pf[mi][ks] = *(const short8*)&psw[(mi * 16 + col) * 72 + ks * 32 + quad * 8];
#pragma unroll
    for (int ks = 0; ks < 2; ++ks) {
      short8 vf[4];
#pragma unroll
      for (int n = 0; n < 4; ++n) {
        const int R = n * 16 + col;
        const int C = (ks * 4 + quad) ^ swz;
        vf[n] = *(const short8*)&Vs[(size_t)(R * 8 + C) * 8];
      }
#pragma unroll
      for (int mi = 0; mi < 2; ++mi)
#pragma unroll
        for (int n = 0; n < 4; ++n)
          acc[mi][n] = __builtin_amdgcn_mfma_f32_16x16x32_bf16(pf[mi][ks], vf[n], acc[mi][n], 0, 0, 0);
    }
    __syncthreads();
  }

  const int b = bh >> 4, h = bh & 15;
#pragma unroll
  for (int mi = 0; mi < 2; ++mi)
#pragma unroll
    for (int r = 0; r < 4; ++r) {
      float s = lsum[mi][r];
      s += __shfl_xor(s, 1, 64);
      s += __shfl_xor(s, 2, 64);
      s += __shfl_xor(s, 4, 64);
      s += __shfl_xor(s, 8, 64);
      const float rl = 1.f / s;
      const size_t ro = (size_t)(b * 2048 + q0 + mi * 16 + quad * 4 + r) * 1024 + h * 64;
#pragma unroll
      for (int n = 0; n < 4; ++n) out[ro + n * 16 + col] = f2bf(acc[mi][n][r] * rl);
    }
}

// ---------------------------------------------------------------------------
// bf16 MFMA GEMM, C = A[M][K] @ BT[N][K]^T. BK=64 (2 k-chunks per barrier),
// XOR chunk swizzle (c ^= r&7) for conflict-free b128 frag reads, LDS-staged
// coalesced epilogue (dwordx4 stores). Split-K via blockIdx.z.
// ---------------------------------------------------------------------------
enum { MODE_QKV = 0, MODE_FF1 = 1, MODE_PART = 2 };

template <int MODE>
__global__ __launch_bounds__(256) void gemm_bt(
    const bf16_t* __restrict__ A, const bf16_t* __restrict__ BT,
    int M, int N, int K, int kspan,
    const float* __restrict__ bias0, const float* __restrict__ bias1,
    const float* __restrict__ bias2,
    bf16_t* __restrict__ ob0, bf16_t* __restrict__ ob1, bf16_t* __restrict__ ob2) {
  // loop phase: As 128x64 bf16 (16 KB) + Bs (16 KB); epilogue: 128x136 bf16 (34816 B)
  __shared__ __align__(16) char smem[34816];
  bf16_t* As = (bf16_t*)smem;
  bf16_t* Bs = (bf16_t*)(smem + 16384);
  const int tid = threadIdx.x;
  const int wave = tid >> 6, lane = tid & 63;
  const int row16 = lane & 15, quad = lane >> 4;
  const int m0 = blockIdx.x * 128, n0 = blockIdx.y * 128;
  const int wm = (wave & 1) << 6, wn = (wave >> 1) << 6;

  f32x4 acc[4][4];
#pragma unroll
  for (int i = 0; i < 4; ++i)
#pragma unroll
    for (int j = 0; j < 4; ++j) acc[i][j] = (f32x4){0.f, 0.f, 0.f, 0.f};

  const int kb = blockIdx.z * kspan;
  const int kend = (kb + kspan < K) ? kb + kspan : K;

  for (int k0 = kb; k0 < kend; k0 += 64) {
#pragma unroll
    for (int j = 0; j < 4; ++j) {
      const int s = j * 256 + tid;
      const int r = s >> 3;
      const int cg = ((s & 7) ^ (r & 7)) << 3;  // element offset of swizzled chunk
      gload_lds16(A + (size_t)(m0 + r) * K + k0 + cg, As + (size_t)s * 8);
      gload_lds16(BT + (size_t)(n0 + r) * K + k0 + cg, Bs + (size_t)s * 8);
    }
    __syncthreads();
    const int sw = row16 & 7;
#pragma unroll
    for (int kk = 0; kk < 2; ++kk) {
      short8 af[4], bfr[4];
#pragma unroll
      for (int mi = 0; mi < 4; ++mi)
        af[mi] = *(const short8*)&As[(size_t)(wm + mi * 16 + row16) * 64 + (((kk << 2) | quad) ^ sw) * 8];
#pragma unroll
      for (int ni = 0; ni < 4; ++ni)
        bfr[ni] = *(const short8*)&Bs[(size_t)(wn + ni * 16 + row16) * 64 + (((kk << 2) | quad) ^ sw) * 8];
#pragma unroll
      for (int mi = 0; mi < 4; ++mi)
#pragma unroll
        for (int ni = 0; ni < 4; ++ni)
          acc[mi][ni] =
              __builtin_amdgcn_mfma_f32_16x16x32_bf16(af[mi], bfr[ni], acc[mi][ni], 0, 0, 0);
    }
    __syncthreads();
  }

  // --- epilogue: bias/activation in regs -> bf16 tile in LDS -> coalesced stores
  bf16_t* ct = (bf16_t*)smem;  // [128][136]
#pragma unroll
  for (int mi = 0; mi < 4; ++mi)
#pragma unroll
    for (int ni = 0; ni < 4; ++ni) {
      const int gn = n0 + wn + ni * 16 + row16;
      float bsv = 0.f;
      if (MODE == MODE_QKV)
        bsv = (gn < 1024) ? bias0[gn] : (gn < 2048) ? bias1[gn - 1024] : bias2[gn - 2048];
      else if (MODE == MODE_FF1)
        bsv = bias0[gn];
#pragma unroll
      for (int r = 0; r < 4; ++r) {
        float c = acc[mi][ni][r] + bsv;
        if (MODE == MODE_FF1) c = fmaxf(c, 0.f);
        ct[(size_t)(wm + mi * 16 + quad * 4 + r) * 136 + wn + ni * 16 + row16] = f2bf(c);
      }
    }
  __syncthreads();
  const int lr0 = tid >> 4, lc = tid & 15;
#pragma unroll
  for (int i = 0; i < 8; ++i) {
    const int lr = i * 16 + lr0;
    const uint4 v = *(const uint4*)&ct[(size_t)lr * 136 + lc * 8];
    const int gm = m0 + lr;
    if (MODE == MODE_QKV) {
      const int nn = (n0 & 1023) + lc * 8;
      const int h = nn >> 6, d = nn & 63;
      const int b = gm >> 11, s = gm & 2047;
      bf16_t* dst = (n0 < 1024) ? ob0 : (n0 < 2048) ? ob1 : ob2;
      *(uint4*)&dst[(((size_t)b * 16 + h) * 2048 + s) * 64 + d] = v;
    } else if (MODE == MODE_FF1) {
      *(uint4*)&ob0[(size_t)gm * N + n0 + lc * 8] = v;
    } else {  // MODE_PART
      bf16_t* dst = (blockIdx.z == 2) ? ob1 : ob0 + (size_t)blockIdx.z * 4194304;
      *(uint4*)&dst[(size_t)gm * N + n0 + lc * 8] = v;
    }
  }
}

// ---------------------------------------------------------------------------
extern "C" void kernel_launch(void* const* d_in, const int* in_sizes, int n_in,
                              void* d_out, int out_size, void* d_ws, size_t ws_size,
                              hipStream_t stream) {
  const float* x = (const float*)d_in[0];
  const float* Wq = (const float*)d_in[1];
  const float* bq = (const float*)d_in[2];
  const float* Wk = (const float*)d_in[3];
  const float* bk = (const float*)d_in[4];
  const float* Wv = (const float*)d_in[5];
  const float* bv = (const float*)d_in[6];
  const float* Wo = (const float*)d_in[7];
  const float* bo = (const float*)d_in[8];
  const float* W1 = (const float*)d_in[9];
  const float* b1 = (const float*)d_in[10];
  const float* W2 = (const float*)d_in[11];
  const float* b2 = (const float*)d_in[12];
  const float* g1 = (const float*)d_in[13];
  const float* be1 = (const float*)d_in[14];
  const float* g2 = (const float*)d_in[15];
  const float* be2 = (const float*)d_in[16];
  float* out = (float*)d_out;

  char* ws = (char*)d_ws;
  size_t off = 0;
  auto alloc = [&](size_t bytes) {
    void* p = ws + off;
    off += (bytes + 255) & ~(size_t)255;
    return p;
  };
  bf16_t* WqkvT = (bf16_t*)alloc(3072ULL * 1024 * 2);  // [0,6MB)
  bf16_t* WoT = (bf16_t*)alloc(1024ULL * 1024 * 2);    // [6,8)
  bf16_t* W1T = (bf16_t*)alloc(4096ULL * 1024 * 2);    // [8,16)
  bf16_t* W2T = (bf16_t*)alloc(1024ULL * 4096 * 2);    // [16,24)
  bf16_t* xnb = (bf16_t*)alloc(4096ULL * 1024 * 2);    // [24,32) xn1/attn_out/xn2/FF2-partial2
  bf16_t* qb = (bf16_t*)alloc(4194304ULL * 2);         // [32,40)
  bf16_t* kb = (bf16_t*)alloc(4194304ULL * 2);         // [40,48)
  bf16_t* vraw = (bf16_t*)alloc(4194304ULL * 2);       // [48,56) V [b,h,s,d]
  bf16_t* vt = (bf16_t*)alloc(4194304ULL * 2);         // [56,64) V^T [b,h,d,s]
  bf16_t* h1 = qb;       // FF1 out [4096][4096] bf16 over [32,64)
  bf16_t* x2p = qb;      // X2 bf16 partials (4 x 8MB) over [32,64), pre-FF1
  bf16_t* ffp = WqkvT;   // FF2 partials 0,1 over dead weights [0,16)
  float* x2 = (float*)alloc(16777216ULL);              // [64,80)

  prep_kernel<<<16384, 256, 0, stream>>>(Wq, Wk, Wv, Wo, W1, W2, x, g1, be1,
                                         WqkvT, W1T, W2T, xnb);

  gemm_bt<MODE_QKV><<<dim3(32, 24, 1), 256, 0, stream>>>(xnb, WqkvT, 4096, 3072, 1024, 1024,
                                                         bq, bk, bv, qb, kb, vraw);

  rope_bf16<<<8192, 256, 0, stream>>>(qb, kb);

  vtrans<<<dim3(32, 64, 2), 256, 0, stream>>>(vraw, vt);

  attn3<<<dim3(32, 16), 256, 0, stream>>>(qb, kb, vt, xnb);

  // X2 = attn_out @ Wo, split-K=4 (kspan 256)
  gemm_bt<MODE_PART><<<dim3(32, 8, 4), 256, 0, stream>>>(xnb, WoT, 4096, 1024, 1024, 256,
                                                         nullptr, nullptr, nullptr,
                                                         x2p, x2p + 2 * 4194304, nullptr);

  ln2_combine<<<4096, 256, 0, stream>>>(x2p, x, bo, g2, be2, x2, xnb);

  gemm_bt<MODE_FF1><<<dim3(32, 32, 1), 256, 0, stream>>>(xnb, W1T, 4096, 4096, 1024, 1024,
                                                         b1, nullptr, nullptr,
                                                         h1, nullptr, nullptr);

  // FF2 = h1 @ W2, split-K=3 (1408/1408/1280; 64-multiples for BK=64)
  gemm_bt<MODE_PART><<<dim3(32, 8, 3), 256, 0, stream>>>(h1, W2T, 4096, 1024, 4096, 1408,
                                                         nullptr, nullptr, nullptr,
                                                         ffp, xnb, nullptr);

  ffn_combine<<<4096, 256, 0, stream>>>(ffp, xnb, x2, b2, out);
}